// Round 1
// baseline (2116.764 us; speedup 1.0000x reference)
//
#include <hip/hip_runtime.h>

#define BATCH 64
#define LHIST 12
#define NNODE 4096
#define CCH   3
#define FD    32
#define HD    64
#define OUTD  12
#define TIDN  288
#define DIWN  7
#define TDD   16
#define EMBD  10
#define MROWS 2048   // BATCH*FD
#define KDIM  4096   // nodes

typedef __attribute__((ext_vector_type(8))) short bf16x8;
typedef __attribute__((ext_vector_type(4))) float f32x4;

__device__ __forceinline__ unsigned short f2b(float f) {
    union { float f; unsigned u; } v; v.f = f;
    unsigned r = v.u + 0x7fffu + ((v.u >> 16) & 1u);
    return (unsigned short)(r >> 16);
}

__device__ __forceinline__ void gl2lds16(const void* g, void* l) {
    __builtin_amdgcn_global_load_lds((__attribute__((address_space(1))) void*)(void*)g,
                                     (__attribute__((address_space(3))) void*)l, 16, 0, 0);
}

// ---------------- A = softmax(relu(emb @ emb^T), axis=-1), stored bf16 row-major ----
__global__ __launch_bounds__(256) void build_A(const float* __restrict__ emb,
                                               unsigned short* __restrict__ A) {
    const int n = blockIdx.x;
    const int tid = threadIdx.x;
    __shared__ float sc[NNODE];
    __shared__ float red[256];
    float e[EMBD];
#pragma unroll
    for (int c = 0; c < EMBD; c++) e[c] = emb[(size_t)n * EMBD + c];
    float mx = 0.f;
    for (int m = tid; m < NNODE; m += 256) {
        float s = 0.f;
#pragma unroll
        for (int c = 0; c < EMBD; c++) s += e[c] * emb[(size_t)m * EMBD + c];
        s = fmaxf(s, 0.f);
        sc[m] = s;
        mx = fmaxf(mx, s);
    }
    red[tid] = mx;
    __syncthreads();
    for (int off = 128; off > 0; off >>= 1) {
        if (tid < off) red[tid] = fmaxf(red[tid], red[tid + off]);
        __syncthreads();
    }
    mx = red[0];
    __syncthreads();
    float sum = 0.f;
    for (int m = tid; m < NNODE; m += 256) {
        float v = expf(sc[m] - mx);
        sc[m] = v;
        sum += v;
    }
    red[tid] = sum;
    __syncthreads();
    for (int off = 128; off > 0; off >>= 1) {
        if (tid < off) red[tid] += red[tid + off];
        __syncthreads();
    }
    const float inv = 1.f / red[0];
    for (int m = tid; m < NNODE; m += 256)
        A[(size_t)n * NNODE + m] = f2b(sc[m] * inv);
}

// ---------------- encoder: field[(b*32+f)][n] (fp32 + bf16 copy) -------------------
__global__ __launch_bounds__(256) void encoder(const float* __restrict__ hist,
                                               const float* __restrict__ tid_emb,
                                               const float* __restrict__ diw_emb,
                                               const float* __restrict__ t2f_w,
                                               const float* __restrict__ t2f_b,
                                               const float* __restrict__ enc_w1,
                                               const float* __restrict__ enc_b1,
                                               const float* __restrict__ enc_w2,
                                               const float* __restrict__ enc_b2,
                                               float* __restrict__ field,
                                               unsigned short* __restrict__ fT) {
    const int gid = blockIdx.x * 256 + threadIdx.x;
    const int b = gid >> 12;
    const int n = gid & (NNODE - 1);
    const float* hb = hist + ((size_t)b * LHIST * NNODE + n) * CCH;
    float x[LHIST * CCH];
#pragma unroll
    for (int l = 0; l < LHIST; l++) {
        x[l * 3 + 0] = hb[(size_t)l * NNODE * CCH + 0];
        x[l * 3 + 1] = hb[(size_t)l * NNODE * CCH + 1];
        x[l * 3 + 2] = hb[(size_t)l * NNODE * CCH + 2];
    }
    float f[FD];
#pragma unroll
    for (int o = 0; o < FD; o++) f[o] = enc_b2[o] + t2f_b[o];
    for (int j = 0; j < HD; j++) {
        float h = enc_b1[j];
#pragma unroll
        for (int k = 0; k < LHIST * CCH; k++) h += x[k] * enc_w1[k * HD + j];
        h = fmaxf(h, 0.f);
#pragma unroll
        for (int o = 0; o < FD; o++) f[o] += h * enc_w2[j * FD + o];
    }
    // temporal embedding (last timestep, channels 1/2)
    const int ti = min(max((int)(x[11 * 3 + 1] * 288.0f), 0), TIDN - 1);
    const int di = min(max((int)(x[11 * 3 + 2] * 7.0f), 0), DIWN - 1);
    for (int g = 0; g < TDD; g++) {
        const float tg = tid_emb[ti * TDD + g];
        const float dg = diw_emb[di * TDD + g];
#pragma unroll
        for (int o = 0; o < FD; o++)
            f[o] += tg * t2f_w[g * FD + o] + dg * t2f_w[(TDD + g) * FD + o];
    }
#pragma unroll
    for (int o = 0; o < FD; o++) {
        const size_t idx = (size_t)(b * FD + o) * NNODE + n;
        field[idx] = f[o];
        fT[idx] = f2b(f[o]);
    }
}

// ---------------- GEMM: C[i][j] = sum_k X[i][k]*Y[j][k], X:(2048,4096) Y:(4096,4096) bf16
__global__ __launch_bounds__(256) void gemm_bt(const unsigned short* __restrict__ X,
                                               const unsigned short* __restrict__ Y,
                                               float* __restrict__ C) {
    constexpr int K = KDIM;
    constexpr int NC = KDIM;
    constexpr int BK = 32;
    __shared__ __align__(16) unsigned short Xs[128 * BK];
    __shared__ __align__(16) unsigned short Ys[128 * BK];
    const int tid = threadIdx.x;
    const int wave = tid >> 6;
    const int lane = tid & 63;
    const int i0 = blockIdx.x * 128;
    const int j0 = blockIdx.y * 128;
    const int wi = (wave >> 1) * 64;
    const int wj = (wave & 1) * 64;

    const int lrow = lane >> 2;        // 0..15
    const int lcol = (lane & 3) * 8;   // element offset (8 bf16 = 16B)

    const unsigned short* Xg = X + (size_t)(i0 + wave * 32 + lrow) * K + lcol;
    const unsigned short* Yg = Y + (size_t)(j0 + wave * 32 + lrow) * K + lcol;
    unsigned short* Xl0 = &Xs[(wave * 32) * BK];
    unsigned short* Xl1 = &Xs[(wave * 32 + 16) * BK];
    unsigned short* Yl0 = &Ys[(wave * 32) * BK];
    unsigned short* Yl1 = &Ys[(wave * 32 + 16) * BK];

    const f32x4 zero = {0.f, 0.f, 0.f, 0.f};
    f32x4 acc[4][4];
#pragma unroll
    for (int a = 0; a < 4; a++)
#pragma unroll
        for (int b = 0; b < 4; b++) acc[a][b] = zero;

    const int fr = lane & 15;
    const int kq = (lane >> 4) * 8;

    for (int kt = 0; kt < K; kt += BK) {
        __syncthreads();
        gl2lds16(Xg + kt, Xl0);
        gl2lds16(Xg + kt + 16 * K, Xl1);
        gl2lds16(Yg + kt, Yl0);
        gl2lds16(Yg + kt + 16 * K, Yl1);
        __syncthreads();
        bf16x8 fa[4], fb[4];
#pragma unroll
        for (int t = 0; t < 4; t++)
            fa[t] = *(const bf16x8*)&Xs[(wi + t * 16 + fr) * BK + kq];
#pragma unroll
        for (int t = 0; t < 4; t++)
            fb[t] = *(const bf16x8*)&Ys[(wj + t * 16 + fr) * BK + kq];
#pragma unroll
        for (int mi = 0; mi < 4; mi++)
#pragma unroll
            for (int ni = 0; ni < 4; ni++)
                acc[mi][ni] = __builtin_amdgcn_mfma_f32_16x16x32_bf16(
                    fa[mi], fb[ni], acc[mi][ni], 0, 0, 0);
    }

    const int r0 = (lane >> 4) * 4;
#pragma unroll
    for (int mi = 0; mi < 4; mi++) {
#pragma unroll
        for (int ni = 0; ni < 4; ni++) {
            const int row = i0 + wi + mi * 16 + r0;
            const int col = j0 + wj + ni * 16 + fr;
#pragma unroll
            for (int r = 0; r < 4; r++)
                C[(size_t)(row + r) * NC + col] = acc[mi][ni][r];
        }
    }
}

// ---------------- per-step pointwise + small matmuls (transposed layout) ------------
__global__ __launch_bounds__(256) void step_update(const float* __restrict__ Ct,
                                                   float* __restrict__ field,
                                                   float* __restrict__ state,
                                                   unsigned short* __restrict__ fT,
                                                   const float* __restrict__ pde_w1,
                                                   const float* __restrict__ pde_b1,
                                                   const float* __restrict__ pde_w2,
                                                   const float* __restrict__ pde_b2,
                                                   const float* __restrict__ ss_win,
                                                   const float* __restrict__ ss_wst,
                                                   const float* __restrict__ ss_b,
                                                   const float* __restrict__ ss_wout,
                                                   const float* __restrict__ ss_bout,
                                                   const float* __restrict__ pde_mix,
                                                   int first) {
    const int gid = blockIdx.x * 256 + threadIdx.x;
    const int b = gid >> 12;
    const int n = gid & (NNODE - 1);
    const size_t base = (size_t)b * FD * NNODE + n;
    const float alpha = 1.f / (1.f + expf(-pde_mix[0]));
    const float dt = 1.0f / 4.0f;

    float ff[FD], st[FD];
#pragma unroll
    for (int f = 0; f < FD; f++) ff[f] = field[base + (size_t)f * NNODE];
    if (first) {
#pragma unroll
        for (int f = 0; f < FD; f++) st[f] = 0.f;
    } else {
#pragma unroll
        for (int f = 0; f < FD; f++) st[f] = state[base + (size_t)f * NNODE];
    }

    // N_F = relu(field@pde_w1 + b1) @ pde_w2 + b2
    float nf[FD];
#pragma unroll
    for (int f = 0; f < FD; f++) nf[f] = pde_b2[f];
    for (int j = 0; j < HD; j++) {
        float h = pde_b1[j];
#pragma unroll
        for (int k = 0; k < FD; k++) h += ff[k] * pde_w1[k * HD + j];
        h = fmaxf(h, 0.f);
#pragma unroll
        for (int f = 0; f < FD; f++) nf[f] += h * pde_w2[j * FD + f];
    }
    // fe = field + (alpha*L_F + (1-alpha)*N_F)*dt   (L_F = Ct - field); store fe in nf
#pragma unroll
    for (int f = 0; f < FD; f++) {
        const float lf = Ct[base + (size_t)f * NNODE] - ff[f];
        nf[f] = ff[f] + (alpha * lf + (1.f - alpha) * nf[f]) * dt;
    }
    // state = tanh(fe@ss_win + state@ss_wst + ss_b)
    float ns[FD];
#pragma unroll
    for (int f = 0; f < FD; f++) ns[f] = ss_b[f];
#pragma unroll
    for (int g = 0; g < FD; g++) {
        const float a_ = nf[g];
        const float s_ = st[g];
#pragma unroll
        for (int f = 0; f < FD; f++)
            ns[f] += a_ * ss_win[g * FD + f] + s_ * ss_wst[g * FD + f];
    }
#pragma unroll
    for (int f = 0; f < FD; f++) ns[f] = tanhf(ns[f]);
    // field = fe + state@ss_wout + ss_bout
#pragma unroll
    for (int f = 0; f < FD; f++) ff[f] = nf[f] + ss_bout[f];
#pragma unroll
    for (int g = 0; g < FD; g++) {
        const float s_ = ns[g];
#pragma unroll
        for (int f = 0; f < FD; f++) ff[f] += s_ * ss_wout[g * FD + f];
    }
#pragma unroll
    for (int f = 0; f < FD; f++) {
        const size_t idx = base + (size_t)f * NNODE;
        field[idx] = ff[f];
        state[idx] = ns[f];
        fT[idx] = f2b(ff[f]);
    }
}

// ---------------- decoder: out[b][o][n][0] = (relu(field@dw1+b1)@dw2+b2)[b][n][o] ---
__global__ __launch_bounds__(256) void decoder(const float* __restrict__ field,
                                               const float* __restrict__ dw1,
                                               const float* __restrict__ db1,
                                               const float* __restrict__ dw2,
                                               const float* __restrict__ db2,
                                               float* __restrict__ out) {
    const int gid = blockIdx.x * 256 + threadIdx.x;
    const int b = gid >> 12;
    const int n = gid & (NNODE - 1);
    const size_t base = (size_t)b * FD * NNODE + n;
    float ff[FD];
#pragma unroll
    for (int f = 0; f < FD; f++) ff[f] = field[base + (size_t)f * NNODE];
    float o[OUTD];
#pragma unroll
    for (int t = 0; t < OUTD; t++) o[t] = db2[t];
    for (int j = 0; j < HD; j++) {
        float h = db1[j];
#pragma unroll
        for (int k = 0; k < FD; k++) h += ff[k] * dw1[k * HD + j];
        h = fmaxf(h, 0.f);
#pragma unroll
        for (int t = 0; t < OUTD; t++) o[t] += h * dw2[j * OUTD + t];
    }
#pragma unroll
    for (int t = 0; t < OUTD; t++)
        out[(size_t)(b * OUTD + t) * NNODE + n] = o[t];
}

extern "C" void kernel_launch(void* const* d_in, const int* in_sizes, int n_in,
                              void* d_out, int out_size, void* d_ws, size_t ws_size,
                              hipStream_t stream) {
    (void)in_sizes; (void)n_in; (void)out_size; (void)ws_size;
    const float* hist    = (const float*)d_in[0];
    const float* tid_emb = (const float*)d_in[5];
    const float* diw_emb = (const float*)d_in[6];
    const float* t2f_w   = (const float*)d_in[7];
    const float* t2f_b   = (const float*)d_in[8];
    const float* enc_w1  = (const float*)d_in[9];
    const float* enc_b1  = (const float*)d_in[10];
    const float* enc_w2  = (const float*)d_in[11];
    const float* enc_b2  = (const float*)d_in[12];
    const float* node_emb= (const float*)d_in[13];
    const float* pde_w1  = (const float*)d_in[14];
    const float* pde_b1  = (const float*)d_in[15];
    const float* pde_w2  = (const float*)d_in[16];
    const float* pde_b2  = (const float*)d_in[17];
    const float* ss_win  = (const float*)d_in[18];
    const float* ss_wst  = (const float*)d_in[19];
    const float* ss_b    = (const float*)d_in[20];
    const float* ss_wout = (const float*)d_in[21];
    const float* ss_bout = (const float*)d_in[22];
    const float* dec_w1  = (const float*)d_in[23];
    const float* dec_b1  = (const float*)d_in[24];
    const float* dec_w2  = (const float*)d_in[25];
    const float* dec_b2  = (const float*)d_in[26];
    const float* pde_mix = (const float*)d_in[27];

    char* w = (char*)d_ws;
    unsigned short* A_bf = (unsigned short*)w;  w += (size_t)KDIM * KDIM * 2;   // 33.5 MB
    unsigned short* fT   = (unsigned short*)w;  w += (size_t)MROWS * KDIM * 2;  // 16.8 MB
    float* field = (float*)w;                   w += (size_t)MROWS * KDIM * 4;  // 33.5 MB
    float* state = (float*)w;                   w += (size_t)MROWS * KDIM * 4;  // 33.5 MB
    float* Ct    = (float*)w;                   w += (size_t)MROWS * KDIM * 4;  // 33.5 MB

    build_A<<<NNODE, 256, 0, stream>>>(node_emb, A_bf);
    encoder<<<(BATCH * NNODE) / 256, 256, 0, stream>>>(hist, tid_emb, diw_emb, t2f_w,
                                                       t2f_b, enc_w1, enc_b1, enc_w2,
                                                       enc_b2, field, fT);
    for (int s = 0; s < 4; s++) {
        gemm_bt<<<dim3(MROWS / 128, KDIM / 128), 256, 0, stream>>>(fT, A_bf, Ct);
        step_update<<<(BATCH * NNODE) / 256, 256, 0, stream>>>(
            Ct, field, state, fT, pde_w1, pde_b1, pde_w2, pde_b2, ss_win, ss_wst,
            ss_b, ss_wout, ss_bout, pde_mix, s == 0 ? 1 : 0);
    }
    decoder<<<(BATCH * NNODE) / 256, 256, 0, stream>>>(field, dec_w1, dec_b1, dec_w2,
                                                       dec_b2, (float*)d_out);
}

// Round 2
// 1283.610 us; speedup vs baseline: 1.6491x; 1.6491x over previous
//
#include <hip/hip_runtime.h>

#define BATCH 64
#define LHIST 12
#define NNODE 4096
#define CCH   3
#define FD    32
#define HD    64
#define OUTD  12
#define TIDN  288
#define DIWN  7
#define TDD   16
#define EMBD  10
#define MROWS 2048   // BATCH*FD
#define KDIM  4096   // nodes

typedef __attribute__((ext_vector_type(8))) short bf16x8;
typedef __attribute__((ext_vector_type(4))) float f32x4;

__device__ __forceinline__ unsigned short f2b(float f) {
    union { float f; unsigned u; } v; v.f = f;
    unsigned r = v.u + 0x7fffu + ((v.u >> 16) & 1u);
    return (unsigned short)(r >> 16);
}

__device__ __forceinline__ float fast_tanh(float x) {
    x = fminf(fmaxf(x, -15.f), 15.f);
    const float e = __expf(2.f * x);
    return (e - 1.f) / (e + 1.f);
}

__device__ __forceinline__ void gl2lds16(const void* g, void* l) {
    __builtin_amdgcn_global_load_lds((__attribute__((address_space(1))) void*)(void*)g,
                                     (__attribute__((address_space(3))) void*)l, 16, 0, 0);
}

// ---------------- A = softmax(relu(emb @ emb^T), axis=-1), stored bf16 row-major ----
__global__ __launch_bounds__(256) void build_A(const float* __restrict__ emb,
                                               unsigned short* __restrict__ A) {
    const int n = blockIdx.x;
    const int tid = threadIdx.x;
    __shared__ float sc[NNODE];
    __shared__ float red[256];
    float e[EMBD];
#pragma unroll
    for (int c = 0; c < EMBD; c++) e[c] = emb[(size_t)n * EMBD + c];
    float mx = 0.f;
    for (int m = tid; m < NNODE; m += 256) {
        float s = 0.f;
#pragma unroll
        for (int c = 0; c < EMBD; c++) s += e[c] * emb[(size_t)m * EMBD + c];
        s = fmaxf(s, 0.f);
        sc[m] = s;
        mx = fmaxf(mx, s);
    }
    red[tid] = mx;
    __syncthreads();
    for (int off = 128; off > 0; off >>= 1) {
        if (tid < off) red[tid] = fmaxf(red[tid], red[tid + off]);
        __syncthreads();
    }
    mx = red[0];
    __syncthreads();
    float sum = 0.f;
    for (int m = tid; m < NNODE; m += 256) {
        float v = expf(sc[m] - mx);
        sc[m] = v;
        sum += v;
    }
    red[tid] = sum;
    __syncthreads();
    for (int off = 128; off > 0; off >>= 1) {
        if (tid < off) red[tid] += red[tid + off];
        __syncthreads();
    }
    const float inv = 1.f / red[0];
    for (int m = tid; m < NNODE; m += 256)
        A[(size_t)n * NNODE + m] = f2b(sc[m] * inv);
}

// ---------------- encoder: field[(b*32+f)][n] (fp32 + bf16 copy) -------------------
__global__ __launch_bounds__(256, 2) void encoder(const float* __restrict__ hist,
                                                  const float* __restrict__ tid_emb,
                                                  const float* __restrict__ diw_emb,
                                                  const float* __restrict__ t2f_w,
                                                  const float* __restrict__ t2f_b,
                                                  const float* __restrict__ enc_w1,
                                                  const float* __restrict__ enc_b1,
                                                  const float* __restrict__ enc_w2,
                                                  const float* __restrict__ enc_b2,
                                                  float* __restrict__ field,
                                                  unsigned short* __restrict__ fT) {
    const int gid = blockIdx.x * 256 + threadIdx.x;
    const int b = gid >> 12;
    const int n = gid & (NNODE - 1);
    const float* hb = hist + ((size_t)b * LHIST * NNODE + n) * CCH;
    float x[LHIST * CCH];
#pragma unroll
    for (int l = 0; l < LHIST; l++) {
        x[l * 3 + 0] = hb[(size_t)l * NNODE * CCH + 0];
        x[l * 3 + 1] = hb[(size_t)l * NNODE * CCH + 1];
        x[l * 3 + 2] = hb[(size_t)l * NNODE * CCH + 2];
    }
    float f[FD];
#pragma unroll
    for (int o = 0; o < FD; o++) f[o] = enc_b2[o] + t2f_b[o];
    for (int j = 0; j < HD; j++) {
        float h = enc_b1[j];
#pragma unroll
        for (int k = 0; k < LHIST * CCH; k++) h += x[k] * enc_w1[k * HD + j];
        h = fmaxf(h, 0.f);
#pragma unroll
        for (int o = 0; o < FD; o++) f[o] += h * enc_w2[j * FD + o];
    }
    // temporal embedding (last timestep, channels 1/2)
    const int ti = min(max((int)(x[11 * 3 + 1] * 288.0f), 0), TIDN - 1);
    const int di = min(max((int)(x[11 * 3 + 2] * 7.0f), 0), DIWN - 1);
    for (int g = 0; g < TDD; g++) {
        const float tg = tid_emb[ti * TDD + g];
        const float dg = diw_emb[di * TDD + g];
#pragma unroll
        for (int o = 0; o < FD; o++)
            f[o] += tg * t2f_w[g * FD + o] + dg * t2f_w[(TDD + g) * FD + o];
    }
#pragma unroll
    for (int o = 0; o < FD; o++) {
        const size_t idx = (size_t)(b * FD + o) * NNODE + n;
        field[idx] = f[o];
        fT[idx] = f2b(f[o]);
    }
}

// ---------------- GEMM: C[i][j] = sum_k X[i][k]*Y[j][k], X:(2048,4096) Y:(4096,4096) bf16
__global__ __launch_bounds__(256) void gemm_bt(const unsigned short* __restrict__ X,
                                               const unsigned short* __restrict__ Y,
                                               float* __restrict__ C) {
    constexpr int K = KDIM;
    constexpr int NC = KDIM;
    constexpr int BK = 32;
    __shared__ __align__(16) unsigned short Xs[128 * BK];
    __shared__ __align__(16) unsigned short Ys[128 * BK];
    const int tid = threadIdx.x;
    const int wave = tid >> 6;
    const int lane = tid & 63;
    const int i0 = blockIdx.x * 128;
    const int j0 = blockIdx.y * 128;
    const int wi = (wave >> 1) * 64;
    const int wj = (wave & 1) * 64;

    const int lrow = lane >> 2;        // 0..15
    const int lcol = (lane & 3) * 8;   // element offset (8 bf16 = 16B)

    const unsigned short* Xg = X + (size_t)(i0 + wave * 32 + lrow) * K + lcol;
    const unsigned short* Yg = Y + (size_t)(j0 + wave * 32 + lrow) * K + lcol;
    unsigned short* Xl0 = &Xs[(wave * 32) * BK];
    unsigned short* Xl1 = &Xs[(wave * 32 + 16) * BK];
    unsigned short* Yl0 = &Ys[(wave * 32) * BK];
    unsigned short* Yl1 = &Ys[(wave * 32 + 16) * BK];

    const f32x4 zero = {0.f, 0.f, 0.f, 0.f};
    f32x4 acc[4][4];
#pragma unroll
    for (int a = 0; a < 4; a++)
#pragma unroll
        for (int b = 0; b < 4; b++) acc[a][b] = zero;

    const int fr = lane & 15;
    const int kq = (lane >> 4) * 8;

    for (int kt = 0; kt < K; kt += BK) {
        __syncthreads();
        gl2lds16(Xg + kt, Xl0);
        gl2lds16(Xg + kt + 16 * K, Xl1);
        gl2lds16(Yg + kt, Yl0);
        gl2lds16(Yg + kt + 16 * K, Yl1);
        __syncthreads();
        bf16x8 fa[4], fb[4];
#pragma unroll
        for (int t = 0; t < 4; t++)
            fa[t] = *(const bf16x8*)&Xs[(wi + t * 16 + fr) * BK + kq];
#pragma unroll
        for (int t = 0; t < 4; t++)
            fb[t] = *(const bf16x8*)&Ys[(wj + t * 16 + fr) * BK + kq];
#pragma unroll
        for (int mi = 0; mi < 4; mi++)
#pragma unroll
            for (int ni = 0; ni < 4; ni++)
                acc[mi][ni] = __builtin_amdgcn_mfma_f32_16x16x32_bf16(
                    fa[mi], fb[ni], acc[mi][ni], 0, 0, 0);
    }

    const int r0 = (lane >> 4) * 4;
#pragma unroll
    for (int mi = 0; mi < 4; mi++) {
#pragma unroll
        for (int ni = 0; ni < 4; ni++) {
            const int row = i0 + wi + mi * 16 + r0;
            const int col = j0 + wj + ni * 16 + fr;
#pragma unroll
            for (int r = 0; r < 4; r++)
                C[(size_t)(row + r) * NC + col] = acc[mi][ni][r];
        }
    }
}

// ---------------- per-step pointwise + small matmuls (transposed layout) ------------
// Spill-free restructure: all global reads prefetched up front, arrays die early,
// __launch_bounds__(256,2) -> VGPR cap 256 (peak live ~140 floats, no scratch).
__global__ __launch_bounds__(256, 2) void step_update(const float* __restrict__ Ct,
                                                      float* __restrict__ field,
                                                      float* __restrict__ state,
                                                      unsigned short* __restrict__ fT,
                                                      const float* __restrict__ pde_w1,
                                                      const float* __restrict__ pde_b1,
                                                      const float* __restrict__ pde_w2,
                                                      const float* __restrict__ pde_b2,
                                                      const float* __restrict__ ss_win,
                                                      const float* __restrict__ ss_wst,
                                                      const float* __restrict__ ss_b,
                                                      const float* __restrict__ ss_wout,
                                                      const float* __restrict__ ss_bout,
                                                      const float* __restrict__ pde_mix,
                                                      int first) {
    const int gid = blockIdx.x * 256 + threadIdx.x;
    const int b = gid >> 12;
    const int n = gid & (NNODE - 1);
    const size_t base = (size_t)b * FD * NNODE + n;
    const float alpha = 1.f / (1.f + __expf(-pde_mix[0]));
    const float dt = 1.0f / 4.0f;

    // ---- prefetch everything (issue all global loads before compute) ----
    float ff[FD], ct[FD], st[FD];
#pragma unroll
    for (int f = 0; f < FD; f++) ff[f] = field[base + (size_t)f * NNODE];
#pragma unroll
    for (int f = 0; f < FD; f++) ct[f] = Ct[base + (size_t)f * NNODE];
    if (first) {
#pragma unroll
        for (int f = 0; f < FD; f++) st[f] = 0.f;
    } else {
#pragma unroll
        for (int f = 0; f < FD; f++) st[f] = state[base + (size_t)f * NNODE];
    }

    // ---- N_F = relu(field@pde_w1 + b1) @ pde_w2 + b2 (weights via s_load) ----
    float nf[FD];
#pragma unroll
    for (int f = 0; f < FD; f++) nf[f] = pde_b2[f];
#pragma unroll 4
    for (int j = 0; j < HD; j++) {
        float h = pde_b1[j];
#pragma unroll
        for (int k = 0; k < FD; k++) h += ff[k] * pde_w1[k * HD + j];
        h = fmaxf(h, 0.f);
#pragma unroll
        for (int f = 0; f < FD; f++) nf[f] += h * pde_w2[j * FD + f];
    }

    // ---- fe = field + (alpha*(Ct-field) + (1-alpha)*N_F)*dt; fe -> ff; ct,nf die ----
#pragma unroll
    for (int f = 0; f < FD; f++)
        ff[f] = ff[f] + (alpha * (ct[f] - ff[f]) + (1.f - alpha) * nf[f]) * dt;

    // ---- ns = tanh(fe@ss_win + st@ss_wst + ss_b); ns -> nf; st dies ----
#pragma unroll
    for (int f = 0; f < FD; f++) nf[f] = ss_b[f];
#pragma unroll
    for (int g = 0; g < FD; g++) {
        const float a_ = ff[g];
        const float s_ = st[g];
#pragma unroll
        for (int f = 0; f < FD; f++)
            nf[f] += a_ * ss_win[g * FD + f] + s_ * ss_wst[g * FD + f];
    }
#pragma unroll
    for (int f = 0; f < FD; f++) nf[f] = fast_tanh(nf[f]);

    // ---- field_new = fe + ns@ss_wout + ss_bout (accumulate into ff) ----
#pragma unroll
    for (int f = 0; f < FD; f++) ff[f] += ss_bout[f];
#pragma unroll
    for (int g = 0; g < FD; g++) {
        const float s_ = nf[g];
#pragma unroll
        for (int f = 0; f < FD; f++) ff[f] += s_ * ss_wout[g * FD + f];
    }

    // ---- stores ----
#pragma unroll
    for (int f = 0; f < FD; f++) {
        const size_t idx = base + (size_t)f * NNODE;
        field[idx] = ff[f];
        state[idx] = nf[f];
        fT[idx] = f2b(ff[f]);
    }
}

// ---------------- decoder: out[b][o][n][0] = (relu(field@dw1+b1)@dw2+b2)[b][n][o] ---
__global__ __launch_bounds__(256, 2) void decoder(const float* __restrict__ field,
                                                  const float* __restrict__ dw1,
                                                  const float* __restrict__ db1,
                                                  const float* __restrict__ dw2,
                                                  const float* __restrict__ db2,
                                                  float* __restrict__ out) {
    const int gid = blockIdx.x * 256 + threadIdx.x;
    const int b = gid >> 12;
    const int n = gid & (NNODE - 1);
    const size_t base = (size_t)b * FD * NNODE + n;
    float ff[FD];
#pragma unroll
    for (int f = 0; f < FD; f++) ff[f] = field[base + (size_t)f * NNODE];
    float o[OUTD];
#pragma unroll
    for (int t = 0; t < OUTD; t++) o[t] = db2[t];
    for (int j = 0; j < HD; j++) {
        float h = db1[j];
#pragma unroll
        for (int k = 0; k < FD; k++) h += ff[k] * dw1[k * HD + j];
        h = fmaxf(h, 0.f);
#pragma unroll
        for (int t = 0; t < OUTD; t++) o[t] += h * dw2[j * OUTD + t];
    }
#pragma unroll
    for (int t = 0; t < OUTD; t++)
        out[(size_t)(b * OUTD + t) * NNODE + n] = o[t];
}

extern "C" void kernel_launch(void* const* d_in, const int* in_sizes, int n_in,
                              void* d_out, int out_size, void* d_ws, size_t ws_size,
                              hipStream_t stream) {
    (void)in_sizes; (void)n_in; (void)out_size; (void)ws_size;
    const float* hist    = (const float*)d_in[0];
    const float* tid_emb = (const float*)d_in[5];
    const float* diw_emb = (const float*)d_in[6];
    const float* t2f_w   = (const float*)d_in[7];
    const float* t2f_b   = (const float*)d_in[8];
    const float* enc_w1  = (const float*)d_in[9];
    const float* enc_b1  = (const float*)d_in[10];
    const float* enc_w2  = (const float*)d_in[11];
    const float* enc_b2  = (const float*)d_in[12];
    const float* node_emb= (const float*)d_in[13];
    const float* pde_w1  = (const float*)d_in[14];
    const float* pde_b1  = (const float*)d_in[15];
    const float* pde_w2  = (const float*)d_in[16];
    const float* pde_b2  = (const float*)d_in[17];
    const float* ss_win  = (const float*)d_in[18];
    const float* ss_wst  = (const float*)d_in[19];
    const float* ss_b    = (const float*)d_in[20];
    const float* ss_wout = (const float*)d_in[21];
    const float* ss_bout = (const float*)d_in[22];
    const float* dec_w1  = (const float*)d_in[23];
    const float* dec_b1  = (const float*)d_in[24];
    const float* dec_w2  = (const float*)d_in[25];
    const float* dec_b2  = (const float*)d_in[26];
    const float* pde_mix = (const float*)d_in[27];

    char* w = (char*)d_ws;
    unsigned short* A_bf = (unsigned short*)w;  w += (size_t)KDIM * KDIM * 2;   // 33.5 MB
    unsigned short* fT   = (unsigned short*)w;  w += (size_t)MROWS * KDIM * 2;  // 16.8 MB
    float* field = (float*)w;                   w += (size_t)MROWS * KDIM * 4;  // 33.5 MB
    float* state = (float*)w;                   w += (size_t)MROWS * KDIM * 4;  // 33.5 MB
    float* Ct    = (float*)w;                   w += (size_t)MROWS * KDIM * 4;  // 33.5 MB

    build_A<<<NNODE, 256, 0, stream>>>(node_emb, A_bf);
    encoder<<<(BATCH * NNODE) / 256, 256, 0, stream>>>(hist, tid_emb, diw_emb, t2f_w,
                                                       t2f_b, enc_w1, enc_b1, enc_w2,
                                                       enc_b2, field, fT);
    for (int s = 0; s < 4; s++) {
        gemm_bt<<<dim3(MROWS / 128, KDIM / 128), 256, 0, stream>>>(fT, A_bf, Ct);
        step_update<<<(BATCH * NNODE) / 256, 256, 0, stream>>>(
            Ct, field, state, fT, pde_w1, pde_b1, pde_w2, pde_b2, ss_win, ss_wst,
            ss_b, ss_wout, ss_bout, pde_mix, s == 0 ? 1 : 0);
    }
    decoder<<<(BATCH * NNODE) / 256, 256, 0, stream>>>(field, dec_w1, dec_b1, dec_w2,
                                                       dec_b2, (float*)d_out);
}

// Round 3
// 819.824 us; speedup vs baseline: 2.5820x; 1.5657x over previous
//
#include <hip/hip_runtime.h>

#define BATCH 64
#define LHIST 12
#define NNODE 4096
#define CCH   3
#define FD    32
#define HD    64
#define OUTD  12
#define TIDN  288
#define DIWN  7
#define TDD   16
#define EMBD  10
#define MROWS 2048   // BATCH*FD  (gemm M)
#define KDIM  4096   // nodes
#define MTOT  (BATCH * NNODE)   // 262144 rows of the step "tall-skinny" matmuls

typedef __attribute__((ext_vector_type(8))) short bf16x8;
typedef __attribute__((ext_vector_type(4))) float f32x4;

union BF8U { bf16x8 v; unsigned short s[8]; };

__device__ __forceinline__ unsigned short f2b(float f) {
    union { float f; unsigned u; } v; v.f = f;
    unsigned r = v.u + 0x7fffu + ((v.u >> 16) & 1u);
    return (unsigned short)(r >> 16);
}

__device__ __forceinline__ float fast_tanh(float x) {
    x = fminf(fmaxf(x, -15.f), 15.f);
    const float e = __expf(2.f * x);
    return (e - 1.f) / (e + 1.f);
}

__device__ __forceinline__ void gl2lds16(const void* g, void* l) {
    __builtin_amdgcn_global_load_lds((__attribute__((address_space(1))) void*)(void*)g,
                                     (__attribute__((address_space(3))) void*)l, 16, 0, 0);
}

__device__ __forceinline__ bf16x8 ldsfrag(const unsigned short* p) {
    return *(const bf16x8*)p;
}

__device__ __forceinline__ bf16x8 pack8(float4 a, float4 b) {
    BF8U u;
    u.s[0] = f2b(a.x); u.s[1] = f2b(a.y); u.s[2] = f2b(a.z); u.s[3] = f2b(a.w);
    u.s[4] = f2b(b.x); u.s[5] = f2b(b.y); u.s[6] = f2b(b.z); u.s[7] = f2b(b.w);
    return u.v;
}

// ---------------- A = softmax(relu(emb @ emb^T), axis=-1), stored bf16 row-major ----
__global__ __launch_bounds__(256) void build_A(const float* __restrict__ emb,
                                               unsigned short* __restrict__ A) {
    const int n = blockIdx.x;
    const int tid = threadIdx.x;
    __shared__ float sc[NNODE];
    __shared__ float red[256];
    float e[EMBD];
#pragma unroll
    for (int c = 0; c < EMBD; c++) e[c] = emb[(size_t)n * EMBD + c];
    float mx = 0.f;
    for (int m = tid; m < NNODE; m += 256) {
        float s = 0.f;
#pragma unroll
        for (int c = 0; c < EMBD; c++) s += e[c] * emb[(size_t)m * EMBD + c];
        s = fmaxf(s, 0.f);
        sc[m] = s;
        mx = fmaxf(mx, s);
    }
    red[tid] = mx;
    __syncthreads();
    for (int off = 128; off > 0; off >>= 1) {
        if (tid < off) red[tid] = fmaxf(red[tid], red[tid + off]);
        __syncthreads();
    }
    mx = red[0];
    __syncthreads();
    float sum = 0.f;
    for (int m = tid; m < NNODE; m += 256) {
        float v = expf(sc[m] - mx);
        sc[m] = v;
        sum += v;
    }
    red[tid] = sum;
    __syncthreads();
    for (int off = 128; off > 0; off >>= 1) {
        if (tid < off) red[tid] += red[tid + off];
        __syncthreads();
    }
    const float inv = 1.f / red[0];
    for (int m = tid; m < NNODE; m += 256)
        A[(size_t)n * NNODE + m] = f2b(sc[m] * inv);
}

// ---------------- encoder: field[(b,n)][f] fp32 (f contiguous) + fT[(b,f)][n] bf16 ---
__global__ __launch_bounds__(256, 2) void encoder(const float* __restrict__ hist,
                                                  const float* __restrict__ tid_emb,
                                                  const float* __restrict__ diw_emb,
                                                  const float* __restrict__ t2f_w,
                                                  const float* __restrict__ t2f_b,
                                                  const float* __restrict__ enc_w1,
                                                  const float* __restrict__ enc_b1,
                                                  const float* __restrict__ enc_w2,
                                                  const float* __restrict__ enc_b2,
                                                  float* __restrict__ field,
                                                  unsigned short* __restrict__ fT) {
    const int gid = blockIdx.x * 256 + threadIdx.x;
    const int b = gid >> 12;
    const int n = gid & (NNODE - 1);
    const float* hb = hist + ((size_t)b * LHIST * NNODE + n) * CCH;
    float x[LHIST * CCH];
#pragma unroll
    for (int l = 0; l < LHIST; l++) {
        x[l * 3 + 0] = hb[(size_t)l * NNODE * CCH + 0];
        x[l * 3 + 1] = hb[(size_t)l * NNODE * CCH + 1];
        x[l * 3 + 2] = hb[(size_t)l * NNODE * CCH + 2];
    }
    float f[FD];
#pragma unroll
    for (int o = 0; o < FD; o++) f[o] = enc_b2[o] + t2f_b[o];
    for (int j = 0; j < HD; j++) {
        float h = enc_b1[j];
#pragma unroll
        for (int k = 0; k < LHIST * CCH; k++) h += x[k] * enc_w1[k * HD + j];
        h = fmaxf(h, 0.f);
#pragma unroll
        for (int o = 0; o < FD; o++) f[o] += h * enc_w2[j * FD + o];
    }
    const int ti = min(max((int)(x[11 * 3 + 1] * 288.0f), 0), TIDN - 1);
    const int di = min(max((int)(x[11 * 3 + 2] * 7.0f), 0), DIWN - 1);
    for (int g = 0; g < TDD; g++) {
        const float tg = tid_emb[ti * TDD + g];
        const float dg = diw_emb[di * TDD + g];
#pragma unroll
        for (int o = 0; o < FD; o++)
            f[o] += tg * t2f_w[g * FD + o] + dg * t2f_w[(TDD + g) * FD + o];
    }
    // field: f contiguous -> float4 stores
#pragma unroll
    for (int o4 = 0; o4 < FD / 4; o4++) {
        float4 v = {f[o4 * 4 + 0], f[o4 * 4 + 1], f[o4 * 4 + 2], f[o4 * 4 + 3]};
        *(float4*)&field[(size_t)gid * FD + o4 * 4] = v;
    }
#pragma unroll
    for (int o = 0; o < FD; o++)
        fT[(size_t)(b * FD + o) * NNODE + n] = f2b(f[o]);
}

// ---------------- GEMM: Ct[(b,n)][f] = sum_k fT[(b,f)][k] * A[n][k] ------------------
__global__ __launch_bounds__(256) void gemm_bt(const unsigned short* __restrict__ X,
                                               const unsigned short* __restrict__ Y,
                                               float* __restrict__ C) {
    constexpr int K = KDIM;
    constexpr int BK = 32;
    __shared__ __align__(16) unsigned short Xs[128 * BK];
    __shared__ __align__(16) unsigned short Ys[128 * BK];
    const int tid = threadIdx.x;
    const int wave = tid >> 6;
    const int lane = tid & 63;
    const int i0 = blockIdx.x * 128;
    const int j0 = blockIdx.y * 128;
    const int wi = (wave >> 1) * 64;
    const int wj = (wave & 1) * 64;

    const int lrow = lane >> 2;
    const int lcol = (lane & 3) * 8;

    const unsigned short* Xg = X + (size_t)(i0 + wave * 32 + lrow) * K + lcol;
    const unsigned short* Yg = Y + (size_t)(j0 + wave * 32 + lrow) * K + lcol;
    unsigned short* Xl0 = &Xs[(wave * 32) * BK];
    unsigned short* Xl1 = &Xs[(wave * 32 + 16) * BK];
    unsigned short* Yl0 = &Ys[(wave * 32) * BK];
    unsigned short* Yl1 = &Ys[(wave * 32 + 16) * BK];

    const f32x4 zero = {0.f, 0.f, 0.f, 0.f};
    f32x4 acc[4][4];
#pragma unroll
    for (int a = 0; a < 4; a++)
#pragma unroll
        for (int b = 0; b < 4; b++) acc[a][b] = zero;

    const int fr = lane & 15;
    const int kq = (lane >> 4) * 8;

    for (int kt = 0; kt < K; kt += BK) {
        __syncthreads();
        gl2lds16(Xg + kt, Xl0);
        gl2lds16(Xg + kt + 16 * K, Xl1);
        gl2lds16(Yg + kt, Yl0);
        gl2lds16(Yg + kt + 16 * K, Yl1);
        __syncthreads();
        bf16x8 fa[4], fb[4];
#pragma unroll
        for (int t = 0; t < 4; t++)
            fa[t] = *(const bf16x8*)&Xs[(wi + t * 16 + fr) * BK + kq];
#pragma unroll
        for (int t = 0; t < 4; t++)
            fb[t] = *(const bf16x8*)&Ys[(wj + t * 16 + fr) * BK + kq];
#pragma unroll
        for (int mi = 0; mi < 4; mi++)
#pragma unroll
            for (int ni = 0; ni < 4; ni++)
                acc[mi][ni] = __builtin_amdgcn_mfma_f32_16x16x32_bf16(
                    fa[mi], fb[ni], acc[mi][ni], 0, 0, 0);
    }

    // epilogue: row=(b,f) col=n  ->  Ct[((b*4096)+col)*32 + f], float4 along f
    const int r0 = (lane >> 4) * 4;
#pragma unroll
    for (int mi = 0; mi < 4; mi++) {
#pragma unroll
        for (int ni = 0; ni < 4; ni++) {
            const int R0 = i0 + wi + mi * 16 + r0;      // (b,f) row; f part = R0&31, multiple of 4
            const int col = j0 + wj + ni * 16 + fr;     // n
            const size_t addr = ((size_t)(R0 >> 5) * NNODE + col) * FD + (R0 & 31);
            *(f32x4*)&C[addr] = acc[mi][ni];
        }
    }
}

// ---------------- fused MFMA step: MLP + linear-state ops on matrix cores -------------
// Layouts: field/state/Ct fp32 [(b,n)][f] (f contiguous); fT bf16 [(b,f)][n].
// Per block: 256 rows m=(b,n); per wave: 64 rows. Weights staged once in LDS (bf16,
// transposed so B-frag k is contiguous). C-layout<->A-layout via padded LDS tiles
// (pads 72/40 keep 16B row alignment; bank aliasing <=2-way = free).
#define HPAD 72
#define FPAD 40
__global__ __launch_bounds__(256, 2) void step_mfma(const float* __restrict__ Ct,
                                                    float* __restrict__ field,
                                                    float* __restrict__ state,
                                                    unsigned short* __restrict__ fT,
                                                    const float* __restrict__ pde_w1,
                                                    const float* __restrict__ pde_b1,
                                                    const float* __restrict__ pde_w2,
                                                    const float* __restrict__ pde_b2,
                                                    const float* __restrict__ ss_win,
                                                    const float* __restrict__ ss_wst,
                                                    const float* __restrict__ ss_b,
                                                    const float* __restrict__ ss_wout,
                                                    const float* __restrict__ ss_bout,
                                                    const float* __restrict__ pde_mix,
                                                    int first) {
    __shared__ __align__(16) unsigned short W1T[HD * FD];      // [j][f]
    __shared__ __align__(16) unsigned short W2T[FD * HD];      // [f_out][j]
    __shared__ __align__(16) unsigned short WinT[FD * FD];     // [f_out][g]
    __shared__ __align__(16) unsigned short WstT[FD * FD];
    __shared__ __align__(16) unsigned short WoutT[FD * FD];
    __shared__ __align__(16) unsigned short Hs[4 * 64 * HPAD]; // per-wave relu(H) tile
    __shared__ __align__(16) unsigned short Fs[4 * 64 * FPAD]; // per-wave fe / S tile

    const int tid = threadIdx.x;
    // ---- stage weights (bf16, transposed) ----
    for (int i = tid; i < HD * FD; i += 256) W1T[(i & 63) * FD + (i >> 6)] = f2b(pde_w1[i]);
    for (int i = tid; i < HD * FD; i += 256) W2T[(i & 31) * HD + (i >> 5)] = f2b(pde_w2[i]);
    for (int i = tid; i < FD * FD; i += 256) {
        WinT [(i & 31) * FD + (i >> 5)] = f2b(ss_win[i]);
        WstT [(i & 31) * FD + (i >> 5)] = f2b(ss_wst[i]);
        WoutT[(i & 31) * FD + (i >> 5)] = f2b(ss_wout[i]);
    }
    __syncthreads();

    const int wv = tid >> 6;
    const int lane = tid & 63;
    const int ln = lane & 15;
    const int q = lane >> 4;
    const int kq = q * 8;
    const int r0 = q * 4;
    const int mw = blockIdx.x * 256 + wv * 64;   // wave's first row (all same b)
    const int b = mw >> 12;
    const int n0 = mw & (NNODE - 1);
    unsigned short* Hw = &Hs[wv * 64 * HPAD];
    unsigned short* Fw = &Fs[wv * 64 * FPAD];

    const float alpha = 1.f / (1.f + __expf(-pde_mix[0]));
    const float dt = 0.25f;

    // ---- weight B-frags (registers, used all phases) ----
    bf16x8 w1f[4], w2f[2][2], winf[2], wstf[2], woutf[2];
#pragma unroll
    for (int nj = 0; nj < 4; nj++) w1f[nj] = ldsfrag(&W1T[(nj * 16 + ln) * FD + kq]);
#pragma unroll
    for (int nf = 0; nf < 2; nf++) {
#pragma unroll
        for (int kk = 0; kk < 2; kk++)
            w2f[nf][kk] = ldsfrag(&W2T[(nf * 16 + ln) * HD + kk * 32 + kq]);
        winf[nf]  = ldsfrag(&WinT [(nf * 16 + ln) * FD + kq]);
        wstf[nf]  = ldsfrag(&WstT [(nf * 16 + ln) * FD + kq]);
        woutf[nf] = ldsfrag(&WoutT[(nf * 16 + ln) * FD + kq]);
    }

    // ---- biases (per-lane columns) ----
    float b1v[4], b2v[2], bsv[2], bov[2];
#pragma unroll
    for (int nj = 0; nj < 4; nj++) b1v[nj] = pde_b1[nj * 16 + ln];
#pragma unroll
    for (int nf = 0; nf < 2; nf++) {
        b2v[nf] = pde_b2[nf * 16 + ln];
        bsv[nf] = ss_b[nf * 16 + ln];
        bov[nf] = ss_bout[nf * 16 + ln];
    }

    // ---- field A-frags (+ state A-frags) from global fp32 ----
    bf16x8 fA[4], stA[4];
#pragma unroll
    for (int mi = 0; mi < 4; mi++) {
        const float4* fp = (const float4*)&field[(size_t)(mw + mi * 16 + ln) * FD + kq];
        fA[mi] = pack8(fp[0], fp[1]);
    }
    if (!first) {
#pragma unroll
        for (int mi = 0; mi < 4; mi++) {
            const float4* sp = (const float4*)&state[(size_t)(mw + mi * 16 + ln) * FD + kq];
            stA[mi] = pack8(sp[0], sp[1]);
        }
    }

    const f32x4 zero = {0.f, 0.f, 0.f, 0.f};

    // ---- H = relu(field @ w1 + b1)  (C layout -> LDS bf16 [m][j]) ----
    f32x4 hc[4][4];
#pragma unroll
    for (int mi = 0; mi < 4; mi++)
#pragma unroll
        for (int nj = 0; nj < 4; nj++)
            hc[mi][nj] = __builtin_amdgcn_mfma_f32_16x16x32_bf16(fA[mi], w1f[nj], zero, 0, 0, 0);
#pragma unroll
    for (int mi = 0; mi < 4; mi++)
#pragma unroll
        for (int nj = 0; nj < 4; nj++)
#pragma unroll
            for (int r = 0; r < 4; r++)
                Hw[(mi * 16 + r0 + r) * HPAD + nj * 16 + ln] =
                    f2b(fmaxf(hc[mi][nj][r] + b1v[nj], 0.f));
    __syncthreads();

    // ---- field & Ct in C-layout (scalar loads, latency hidden by NF mfma) ----
    float fld[4][2][4], ctv[4][2][4];
#pragma unroll
    for (int mi = 0; mi < 4; mi++)
#pragma unroll
        for (int nf = 0; nf < 2; nf++)
#pragma unroll
            for (int r = 0; r < 4; r++) {
                const size_t idx = (size_t)(mw + mi * 16 + r0 + r) * FD + nf * 16 + ln;
                fld[mi][nf][r] = field[idx];
                ctv[mi][nf][r] = Ct[idx];
            }

    // ---- N_F = H @ w2 + b2 ----
    bf16x8 hA[4][2];
#pragma unroll
    for (int mi = 0; mi < 4; mi++)
#pragma unroll
        for (int kk = 0; kk < 2; kk++)
            hA[mi][kk] = ldsfrag(&Hw[(mi * 16 + ln) * HPAD + kk * 32 + kq]);
    f32x4 nc[4][2];
#pragma unroll
    for (int mi = 0; mi < 4; mi++)
#pragma unroll
        for (int nf = 0; nf < 2; nf++) {
            f32x4 a = __builtin_amdgcn_mfma_f32_16x16x32_bf16(hA[mi][0], w2f[nf][0], zero, 0, 0, 0);
            nc[mi][nf] = __builtin_amdgcn_mfma_f32_16x16x32_bf16(hA[mi][1], w2f[nf][1], a, 0, 0, 0);
        }

    // ---- fe = field + (alpha*(Ct-field) + (1-alpha)*N_F)*dt  (fp32, C layout) ----
    float fe[4][2][4];
#pragma unroll
    for (int mi = 0; mi < 4; mi++)
#pragma unroll
        for (int nf = 0; nf < 2; nf++)
#pragma unroll
            for (int r = 0; r < 4; r++) {
                const float nfv = nc[mi][nf][r] + b2v[nf];
                const float fv = fld[mi][nf][r];
                fe[mi][nf][r] = fv + (alpha * (ctv[mi][nf][r] - fv) + (1.f - alpha) * nfv) * dt;
                Fw[(mi * 16 + r0 + r) * FPAD + nf * 16 + ln] = f2b(fe[mi][nf][r]);
            }
    __syncthreads();

    // ---- S = tanh(fe @ win + st @ wst + b) ----
    bf16x8 feA[4];
#pragma unroll
    for (int mi = 0; mi < 4; mi++) feA[mi] = ldsfrag(&Fw[(mi * 16 + ln) * FPAD + kq]);
    f32x4 sc_[4][2];
#pragma unroll
    for (int mi = 0; mi < 4; mi++)
#pragma unroll
        for (int nf = 0; nf < 2; nf++) {
            f32x4 a = __builtin_amdgcn_mfma_f32_16x16x32_bf16(feA[mi], winf[nf], zero, 0, 0, 0);
            if (!first)
                a = __builtin_amdgcn_mfma_f32_16x16x32_bf16(stA[mi], wstf[nf], a, 0, 0, 0);
            sc_[mi][nf] = a;
        }
    float sval[4][2][4];
#pragma unroll
    for (int mi = 0; mi < 4; mi++)
#pragma unroll
        for (int nf = 0; nf < 2; nf++)
#pragma unroll
            for (int r = 0; r < 4; r++) {
                sval[mi][nf][r] = fast_tanh(sc_[mi][nf][r] + bsv[nf]);
            }
    __syncthreads();   // all feA reads done before S overwrites Fw
#pragma unroll
    for (int mi = 0; mi < 4; mi++)
#pragma unroll
        for (int nf = 0; nf < 2; nf++)
#pragma unroll
            for (int r = 0; r < 4; r++)
                Fw[(mi * 16 + r0 + r) * FPAD + nf * 16 + ln] = f2b(sval[mi][nf][r]);
    __syncthreads();

    // ---- field_new = fe + S @ wout + bout; stores ----
    bf16x8 SA[4];
#pragma unroll
    for (int mi = 0; mi < 4; mi++) SA[mi] = ldsfrag(&Fw[(mi * 16 + ln) * FPAD + kq]);
#pragma unroll
    for (int mi = 0; mi < 4; mi++) {
#pragma unroll
        for (int nf = 0; nf < 2; nf++) {
            f32x4 oc = __builtin_amdgcn_mfma_f32_16x16x32_bf16(SA[mi], woutf[nf], zero, 0, 0, 0);
            float fnew[4];
#pragma unroll
            for (int r = 0; r < 4; r++) {
                fnew[r] = fe[mi][nf][r] + oc[r] + bov[nf];
                const size_t idx = (size_t)(mw + mi * 16 + r0 + r) * FD + nf * 16 + ln;
                field[idx] = fnew[r];
                state[idx] = sval[mi][nf][r];
            }
            ushort4 pk = {f2b(fnew[0]), f2b(fnew[1]), f2b(fnew[2]), f2b(fnew[3])};
            const size_t ft_addr = (size_t)(b * FD + nf * 16 + ln) * NNODE + n0 + mi * 16 + r0;
            *(ushort4*)&fT[ft_addr] = pk;
        }
    }
}

// ---------------- decoder: reads field [(b,n)][f] (vec4), writes out[b][o][n] --------
__global__ __launch_bounds__(256, 2) void decoder(const float* __restrict__ field,
                                                  const float* __restrict__ dw1,
                                                  const float* __restrict__ db1,
                                                  const float* __restrict__ dw2,
                                                  const float* __restrict__ db2,
                                                  float* __restrict__ out) {
    const int gid = blockIdx.x * 256 + threadIdx.x;
    const int b = gid >> 12;
    const int n = gid & (NNODE - 1);
    float ff[FD];
#pragma unroll
    for (int o4 = 0; o4 < FD / 4; o4++) {
        float4 v = *(const float4*)&field[(size_t)gid * FD + o4 * 4];
        ff[o4 * 4 + 0] = v.x; ff[o4 * 4 + 1] = v.y; ff[o4 * 4 + 2] = v.z; ff[o4 * 4 + 3] = v.w;
    }
    float o[OUTD];
#pragma unroll
    for (int t = 0; t < OUTD; t++) o[t] = db2[t];
    for (int j = 0; j < HD; j++) {
        float h = db1[j];
#pragma unroll
        for (int k = 0; k < FD; k++) h += ff[k] * dw1[k * HD + j];
        h = fmaxf(h, 0.f);
#pragma unroll
        for (int t = 0; t < OUTD; t++) o[t] += h * dw2[j * OUTD + t];
    }
#pragma unroll
    for (int t = 0; t < OUTD; t++)
        out[(size_t)(b * OUTD + t) * NNODE + n] = o[t];
}

extern "C" void kernel_launch(void* const* d_in, const int* in_sizes, int n_in,
                              void* d_out, int out_size, void* d_ws, size_t ws_size,
                              hipStream_t stream) {
    (void)in_sizes; (void)n_in; (void)out_size; (void)ws_size;
    const float* hist    = (const float*)d_in[0];
    const float* tid_emb = (const float*)d_in[5];
    const float* diw_emb = (const float*)d_in[6];
    const float* t2f_w   = (const float*)d_in[7];
    const float* t2f_b   = (const float*)d_in[8];
    const float* enc_w1  = (const float*)d_in[9];
    const float* enc_b1  = (const float*)d_in[10];
    const float* enc_w2  = (const float*)d_in[11];
    const float* enc_b2  = (const float*)d_in[12];
    const float* node_emb= (const float*)d_in[13];
    const float* pde_w1  = (const float*)d_in[14];
    const float* pde_b1  = (const float*)d_in[15];
    const float* pde_w2  = (const float*)d_in[16];
    const float* pde_b2  = (const float*)d_in[17];
    const float* ss_win  = (const float*)d_in[18];
    const float* ss_wst  = (const float*)d_in[19];
    const float* ss_b    = (const float*)d_in[20];
    const float* ss_wout = (const float*)d_in[21];
    const float* ss_bout = (const float*)d_in[22];
    const float* dec_w1  = (const float*)d_in[23];
    const float* dec_b1  = (const float*)d_in[24];
    const float* dec_w2  = (const float*)d_in[25];
    const float* dec_b2  = (const float*)d_in[26];
    const float* pde_mix = (const float*)d_in[27];

    char* w = (char*)d_ws;
    unsigned short* A_bf = (unsigned short*)w;  w += (size_t)KDIM * KDIM * 2;   // 33.5 MB
    unsigned short* fT   = (unsigned short*)w;  w += (size_t)MROWS * KDIM * 2;  // 16.8 MB
    float* field = (float*)w;                   w += (size_t)MTOT * FD * 4;     // 33.5 MB
    float* state = (float*)w;                   w += (size_t)MTOT * FD * 4;     // 33.5 MB
    float* Ct    = (float*)w;                   w += (size_t)MTOT * FD * 4;     // 33.5 MB

    build_A<<<NNODE, 256, 0, stream>>>(node_emb, A_bf);
    encoder<<<(BATCH * NNODE) / 256, 256, 0, stream>>>(hist, tid_emb, diw_emb, t2f_w,
                                                       t2f_b, enc_w1, enc_b1, enc_w2,
                                                       enc_b2, field, fT);
    for (int s = 0; s < 4; s++) {
        gemm_bt<<<dim3(MROWS / 128, KDIM / 128), 256, 0, stream>>>(fT, A_bf, Ct);
        step_mfma<<<MTOT / 256, 256, 0, stream>>>(
            Ct, field, state, fT, pde_w1, pde_b1, pde_w2, pde_b2, ss_win, ss_wst,
            ss_b, ss_wout, ss_bout, pde_mix, s == 0 ? 1 : 0);
    }
    decoder<<<(BATCH * NNODE) / 256, 256, 0, stream>>>(field, dec_w1, dec_b1, dec_w2,
                                                       dec_b2, (float*)d_out);
}

// Round 4
// 769.858 us; speedup vs baseline: 2.7496x; 1.0649x over previous
//
#include <hip/hip_runtime.h>

#define BATCH 64
#define LHIST 12
#define NNODE 4096
#define CCH   3
#define FD    32
#define HD    64
#define OUTD  12
#define TIDN  288
#define DIWN  7
#define TDD   16
#define EMBD  10
#define MROWS 2048   // BATCH*FD  (gemm M)
#define KDIM  4096   // nodes
#define MTOT  (BATCH * NNODE)

typedef __attribute__((ext_vector_type(8))) short bf16x8;
typedef __attribute__((ext_vector_type(4))) float f32x4;

union BF8U { bf16x8 v; unsigned short s[8]; };

__device__ __forceinline__ unsigned short f2b(float f) {
    union { float f; unsigned u; } v; v.f = f;
    unsigned r = v.u + 0x7fffu + ((v.u >> 16) & 1u);
    return (unsigned short)(r >> 16);
}

__device__ __forceinline__ float b2f(unsigned short u) {
    union { unsigned u; float f; } v; v.u = (unsigned)u << 16; return v.f;
}

__device__ __forceinline__ float fast_tanh(float x) {
    x = fminf(fmaxf(x, -15.f), 15.f);
    const float e = __expf(2.f * x);
    return (e - 1.f) / (e + 1.f);
}

__device__ __forceinline__ void gl2lds16(const void* g, void* l) {
    __builtin_amdgcn_global_load_lds((__attribute__((address_space(1))) void*)(void*)g,
                                     (__attribute__((address_space(3))) void*)l, 16, 0, 0);
}

__device__ __forceinline__ bf16x8 ldsfrag(const unsigned short* p) {
    return *(const bf16x8*)p;
}

__device__ __forceinline__ bf16x8 pack8(float4 a, float4 b) {
    BF8U u;
    u.s[0] = f2b(a.x); u.s[1] = f2b(a.y); u.s[2] = f2b(a.z); u.s[3] = f2b(a.w);
    u.s[4] = f2b(b.x); u.s[5] = f2b(b.y); u.s[6] = f2b(b.z); u.s[7] = f2b(b.w);
    return u.v;
}

// ---------------- A = softmax(relu(emb @ emb^T), axis=-1), stored bf16 row-major ----
__global__ __launch_bounds__(256) void build_A(const float* __restrict__ emb,
                                               unsigned short* __restrict__ A) {
    const int n = blockIdx.x;
    const int tid = threadIdx.x;
    __shared__ float sc[NNODE];
    __shared__ float red[256];
    float e[EMBD];
#pragma unroll
    for (int c = 0; c < EMBD; c++) e[c] = emb[(size_t)n * EMBD + c];
    float mx = 0.f;
    for (int m = tid; m < NNODE; m += 256) {
        float s = 0.f;
#pragma unroll
        for (int c = 0; c < EMBD; c++) s += e[c] * emb[(size_t)m * EMBD + c];
        s = fmaxf(s, 0.f);
        sc[m] = s;
        mx = fmaxf(mx, s);
    }
    red[tid] = mx;
    __syncthreads();
    for (int off = 128; off > 0; off >>= 1) {
        if (tid < off) red[tid] = fmaxf(red[tid], red[tid + off]);
        __syncthreads();
    }
    mx = red[0];
    __syncthreads();
    float sum = 0.f;
    for (int m = tid; m < NNODE; m += 256) {
        float v = expf(sc[m] - mx);
        sc[m] = v;
        sum += v;
    }
    red[tid] = sum;
    __syncthreads();
    for (int off = 128; off > 0; off >>= 1) {
        if (tid < off) red[tid] += red[tid + off];
        __syncthreads();
    }
    const float inv = 1.f / red[0];
    for (int m = tid; m < NNODE; m += 256)
        A[(size_t)n * NNODE + m] = f2b(sc[m] * inv);
}

// ---------------- encoder: field[(b,n)][f] fp32 + fT[(b,f)][n] bf16 ------------------
__global__ __launch_bounds__(256, 2) void encoder(const float* __restrict__ hist,
                                                  const float* __restrict__ tid_emb,
                                                  const float* __restrict__ diw_emb,
                                                  const float* __restrict__ t2f_w,
                                                  const float* __restrict__ t2f_b,
                                                  const float* __restrict__ enc_w1,
                                                  const float* __restrict__ enc_b1,
                                                  const float* __restrict__ enc_w2,
                                                  const float* __restrict__ enc_b2,
                                                  float* __restrict__ field,
                                                  unsigned short* __restrict__ fT) {
    const int gid = blockIdx.x * 256 + threadIdx.x;
    const int b = gid >> 12;
    const int n = gid & (NNODE - 1);
    const float* hb = hist + ((size_t)b * LHIST * NNODE + n) * CCH;
    float x[LHIST * CCH];
#pragma unroll
    for (int l = 0; l < LHIST; l++) {
        x[l * 3 + 0] = hb[(size_t)l * NNODE * CCH + 0];
        x[l * 3 + 1] = hb[(size_t)l * NNODE * CCH + 1];
        x[l * 3 + 2] = hb[(size_t)l * NNODE * CCH + 2];
    }
    float f[FD];
#pragma unroll
    for (int o = 0; o < FD; o++) f[o] = enc_b2[o] + t2f_b[o];
    for (int j = 0; j < HD; j++) {
        float h = enc_b1[j];
#pragma unroll
        for (int k = 0; k < LHIST * CCH; k++) h += x[k] * enc_w1[k * HD + j];
        h = fmaxf(h, 0.f);
#pragma unroll
        for (int o = 0; o < FD; o++) f[o] += h * enc_w2[j * FD + o];
    }
    const int ti = min(max((int)(x[11 * 3 + 1] * 288.0f), 0), TIDN - 1);
    const int di = min(max((int)(x[11 * 3 + 2] * 7.0f), 0), DIWN - 1);
    for (int g = 0; g < TDD; g++) {
        const float tg = tid_emb[ti * TDD + g];
        const float dg = diw_emb[di * TDD + g];
#pragma unroll
        for (int o = 0; o < FD; o++)
            f[o] += tg * t2f_w[g * FD + o] + dg * t2f_w[(TDD + g) * FD + o];
    }
#pragma unroll
    for (int o4 = 0; o4 < FD / 4; o4++) {
        float4 v = {f[o4 * 4 + 0], f[o4 * 4 + 1], f[o4 * 4 + 2], f[o4 * 4 + 3]};
        *(float4*)&field[(size_t)gid * FD + o4 * 4] = v;
    }
#pragma unroll
    for (int o = 0; o < FD; o++)
        fT[(size_t)(b * FD + o) * NNODE + n] = f2b(f[o]);
}

// ---------------- split-K GEMM: Cpart[z][(b,n)][f] (bf16) = sum_{k in half z} --------
// XOR bank-swizzle: LDS row r stores global k-chunk c at position c^((r>>1)&3)
// (16B chunks). Makes all ds_read_b128 exactly 2-way per bank = free (m136).
__global__ __launch_bounds__(256) void gemm_bt(const unsigned short* __restrict__ X,
                                               const unsigned short* __restrict__ Y,
                                               unsigned short* __restrict__ Cp) {
    constexpr int K = KDIM;
    constexpr int KS = KDIM / 2;
    constexpr int BK = 32;
    __shared__ __align__(16) unsigned short Xs[128 * BK];
    __shared__ __align__(16) unsigned short Ys[128 * BK];
    const int tid = threadIdx.x;
    const int wave = tid >> 6;
    const int lane = tid & 63;

    // XCD-aware remap: each XCD owns 4 consecutive j-tiles (A rows), streams i.
    const int l = blockIdx.x + 16 * blockIdx.y;   // 0..511
    const int xcd = l & 7;
    const int rem = l >> 3;
    const int by = xcd * 4 + (rem & 3);           // 0..31
    const int bx = rem >> 2;                      // 0..15
    const int i0 = bx * 128;
    const int j0 = by * 128;
    const int k0 = blockIdx.z * KS;
    unsigned short* C = Cp + (size_t)blockIdx.z * MTOT * FD;

    const int wi = (wave >> 1) * 64;
    const int wj = (wave & 1) * 64;

    // staging: lane -> (row lane>>2, swizzled 16B chunk)
    const int lrow = lane >> 2;                                  // 0..15
    const int lcol = ((lane & 3) ^ ((lane >> 3) & 3)) * 8;       // swizzled chunk

    const unsigned short* Xg = X + (size_t)(i0 + wave * 32 + lrow) * K + k0 + lcol;
    const unsigned short* Yg = Y + (size_t)(j0 + wave * 32 + lrow) * K + k0 + lcol;
    unsigned short* Xl0 = &Xs[(wave * 32) * BK];
    unsigned short* Xl1 = &Xs[(wave * 32 + 16) * BK];
    unsigned short* Yl0 = &Ys[(wave * 32) * BK];
    unsigned short* Yl1 = &Ys[(wave * 32 + 16) * BK];

    const f32x4 zero = {0.f, 0.f, 0.f, 0.f};
    f32x4 acc[4][4];
#pragma unroll
    for (int a = 0; a < 4; a++)
#pragma unroll
        for (int b = 0; b < 4; b++) acc[a][b] = zero;

    const int fr = lane & 15;
    const int q = lane >> 4;
    const int kq = (q ^ ((fr >> 1) & 3)) * 8;     // de-swizzled frag chunk

    for (int kt = 0; kt < KS; kt += BK) {
        __syncthreads();
        gl2lds16(Xg + kt, Xl0);
        gl2lds16(Xg + kt + 16 * K, Xl1);
        gl2lds16(Yg + kt, Yl0);
        gl2lds16(Yg + kt + 16 * K, Yl1);
        __syncthreads();
        bf16x8 fa[4], fb[4];
#pragma unroll
        for (int t = 0; t < 4; t++)
            fa[t] = *(const bf16x8*)&Xs[(wi + t * 16 + fr) * BK + kq];
#pragma unroll
        for (int t = 0; t < 4; t++)
            fb[t] = *(const bf16x8*)&Ys[(wj + t * 16 + fr) * BK + kq];
#pragma unroll
        for (int mi = 0; mi < 4; mi++)
#pragma unroll
            for (int ni = 0; ni < 4; ni++)
                acc[mi][ni] = __builtin_amdgcn_mfma_f32_16x16x32_bf16(
                    fa[mi], fb[ni], acc[mi][ni], 0, 0, 0);
    }

    // epilogue: row=(b,f) col=n  ->  bf16 partial at [((b*4096)+col)*32 + f]
    const int r0 = q * 4;
#pragma unroll
    for (int mi = 0; mi < 4; mi++) {
#pragma unroll
        for (int ni = 0; ni < 4; ni++) {
            const int R0 = i0 + wi + mi * 16 + r0;
            const int col = j0 + wj + ni * 16 + fr;
            const size_t addr = ((size_t)(R0 >> 5) * NNODE + col) * FD + (R0 & 31);
            ushort4 pk = {f2b(acc[mi][ni][0]), f2b(acc[mi][ni][1]),
                          f2b(acc[mi][ni][2]), f2b(acc[mi][ni][3])};
            *(ushort4*)&C[addr] = pk;
        }
    }
}

// ---------------- fused MFMA step (bf16 Ct partials, bf16 state) ---------------------
#define HPAD 72
#define FPAD 40
__global__ __launch_bounds__(256, 2) void step_mfma(const unsigned short* __restrict__ Ct0,
                                                    const unsigned short* __restrict__ Ct1,
                                                    float* __restrict__ field,
                                                    unsigned short* __restrict__ state,
                                                    unsigned short* __restrict__ fT,
                                                    const float* __restrict__ pde_w1,
                                                    const float* __restrict__ pde_b1,
                                                    const float* __restrict__ pde_w2,
                                                    const float* __restrict__ pde_b2,
                                                    const float* __restrict__ ss_win,
                                                    const float* __restrict__ ss_wst,
                                                    const float* __restrict__ ss_b,
                                                    const float* __restrict__ ss_wout,
                                                    const float* __restrict__ ss_bout,
                                                    const float* __restrict__ pde_mix,
                                                    int first) {
    __shared__ __align__(16) unsigned short W1T[HD * FD];
    __shared__ __align__(16) unsigned short W2T[FD * HD];
    __shared__ __align__(16) unsigned short WinT[FD * FD];
    __shared__ __align__(16) unsigned short WstT[FD * FD];
    __shared__ __align__(16) unsigned short WoutT[FD * FD];
    __shared__ __align__(16) unsigned short Hs[4 * 64 * HPAD];
    __shared__ __align__(16) unsigned short Fs[4 * 64 * FPAD];

    const int tid = threadIdx.x;
    for (int i = tid; i < HD * FD; i += 256) W1T[(i & 63) * FD + (i >> 6)] = f2b(pde_w1[i]);
    for (int i = tid; i < HD * FD; i += 256) W2T[(i & 31) * HD + (i >> 5)] = f2b(pde_w2[i]);
    for (int i = tid; i < FD * FD; i += 256) {
        WinT [(i & 31) * FD + (i >> 5)] = f2b(ss_win[i]);
        WstT [(i & 31) * FD + (i >> 5)] = f2b(ss_wst[i]);
        WoutT[(i & 31) * FD + (i >> 5)] = f2b(ss_wout[i]);
    }
    __syncthreads();

    const int wv = tid >> 6;
    const int lane = tid & 63;
    const int ln = lane & 15;
    const int q = lane >> 4;
    const int kq = q * 8;
    const int r0 = q * 4;
    const int mw = blockIdx.x * 256 + wv * 64;
    const int b = mw >> 12;
    const int n0 = mw & (NNODE - 1);
    unsigned short* Hw = &Hs[wv * 64 * HPAD];
    unsigned short* Fw = &Fs[wv * 64 * FPAD];

    const float alpha = 1.f / (1.f + __expf(-pde_mix[0]));
    const float dt = 0.25f;

    bf16x8 w1f[4], w2f[2][2], winf[2], wstf[2], woutf[2];
#pragma unroll
    for (int nj = 0; nj < 4; nj++) w1f[nj] = ldsfrag(&W1T[(nj * 16 + ln) * FD + kq]);
#pragma unroll
    for (int nf = 0; nf < 2; nf++) {
#pragma unroll
        for (int kk = 0; kk < 2; kk++)
            w2f[nf][kk] = ldsfrag(&W2T[(nf * 16 + ln) * HD + kk * 32 + kq]);
        winf[nf]  = ldsfrag(&WinT [(nf * 16 + ln) * FD + kq]);
        wstf[nf]  = ldsfrag(&WstT [(nf * 16 + ln) * FD + kq]);
        woutf[nf] = ldsfrag(&WoutT[(nf * 16 + ln) * FD + kq]);
    }

    float b1v[4], b2v[2], bsv[2], bov[2];
#pragma unroll
    for (int nj = 0; nj < 4; nj++) b1v[nj] = pde_b1[nj * 16 + ln];
#pragma unroll
    for (int nf = 0; nf < 2; nf++) {
        b2v[nf] = pde_b2[nf * 16 + ln];
        bsv[nf] = ss_b[nf * 16 + ln];
        bov[nf] = ss_bout[nf * 16 + ln];
    }

    bf16x8 fA[4], stA[4];
#pragma unroll
    for (int mi = 0; mi < 4; mi++) {
        const float4* fp = (const float4*)&field[(size_t)(mw + mi * 16 + ln) * FD + kq];
        fA[mi] = pack8(fp[0], fp[1]);
    }
    if (!first) {
#pragma unroll
        for (int mi = 0; mi < 4; mi++)
            stA[mi] = *(const bf16x8*)&state[(size_t)(mw + mi * 16 + ln) * FD + kq];
    }

    const f32x4 zero = {0.f, 0.f, 0.f, 0.f};

    // ---- H = relu(field @ w1 + b1) ----
    f32x4 hc[4][4];
#pragma unroll
    for (int mi = 0; mi < 4; mi++)
#pragma unroll
        for (int nj = 0; nj < 4; nj++)
            hc[mi][nj] = __builtin_amdgcn_mfma_f32_16x16x32_bf16(fA[mi], w1f[nj], zero, 0, 0, 0);
#pragma unroll
    for (int mi = 0; mi < 4; mi++)
#pragma unroll
        for (int nj = 0; nj < 4; nj++)
#pragma unroll
            for (int r = 0; r < 4; r++)
                Hw[(mi * 16 + r0 + r) * HPAD + nj * 16 + ln] =
                    f2b(fmaxf(hc[mi][nj][r] + b1v[nj], 0.f));
    __syncthreads();

    // ---- field & Ct (=Ct0+Ct1) in C-layout ----
    float fld[4][2][4], ctv[4][2][4];
#pragma unroll
    for (int mi = 0; mi < 4; mi++)
#pragma unroll
        for (int nf = 0; nf < 2; nf++)
#pragma unroll
            for (int r = 0; r < 4; r++) {
                const size_t idx = (size_t)(mw + mi * 16 + r0 + r) * FD + nf * 16 + ln;
                fld[mi][nf][r] = field[idx];
                ctv[mi][nf][r] = b2f(Ct0[idx]) + b2f(Ct1[idx]);
            }

    // ---- N_F = H @ w2 + b2 ----
    bf16x8 hA[4][2];
#pragma unroll
    for (int mi = 0; mi < 4; mi++)
#pragma unroll
        for (int kk = 0; kk < 2; kk++)
            hA[mi][kk] = ldsfrag(&Hw[(mi * 16 + ln) * HPAD + kk * 32 + kq]);
    f32x4 nc[4][2];
#pragma unroll
    for (int mi = 0; mi < 4; mi++)
#pragma unroll
        for (int nf = 0; nf < 2; nf++) {
            f32x4 a = __builtin_amdgcn_mfma_f32_16x16x32_bf16(hA[mi][0], w2f[nf][0], zero, 0, 0, 0);
            nc[mi][nf] = __builtin_amdgcn_mfma_f32_16x16x32_bf16(hA[mi][1], w2f[nf][1], a, 0, 0, 0);
        }

    // ---- fe ----
    float fe[4][2][4];
#pragma unroll
    for (int mi = 0; mi < 4; mi++)
#pragma unroll
        for (int nf = 0; nf < 2; nf++)
#pragma unroll
            for (int r = 0; r < 4; r++) {
                const float nfv = nc[mi][nf][r] + b2v[nf];
                const float fv = fld[mi][nf][r];
                fe[mi][nf][r] = fv + (alpha * (ctv[mi][nf][r] - fv) + (1.f - alpha) * nfv) * dt;
                Fw[(mi * 16 + r0 + r) * FPAD + nf * 16 + ln] = f2b(fe[mi][nf][r]);
            }
    __syncthreads();

    // ---- S = tanh(fe @ win + st @ wst + b) ----
    bf16x8 feA[4];
#pragma unroll
    for (int mi = 0; mi < 4; mi++) feA[mi] = ldsfrag(&Fw[(mi * 16 + ln) * FPAD + kq]);
    f32x4 sc_[4][2];
#pragma unroll
    for (int mi = 0; mi < 4; mi++)
#pragma unroll
        for (int nf = 0; nf < 2; nf++) {
            f32x4 a = __builtin_amdgcn_mfma_f32_16x16x32_bf16(feA[mi], winf[nf], zero, 0, 0, 0);
            if (!first)
                a = __builtin_amdgcn_mfma_f32_16x16x32_bf16(stA[mi], wstf[nf], a, 0, 0, 0);
            sc_[mi][nf] = a;
        }
    float sval[4][2][4];
#pragma unroll
    for (int mi = 0; mi < 4; mi++)
#pragma unroll
        for (int nf = 0; nf < 2; nf++)
#pragma unroll
            for (int r = 0; r < 4; r++)
                sval[mi][nf][r] = fast_tanh(sc_[mi][nf][r] + bsv[nf]);
    __syncthreads();
#pragma unroll
    for (int mi = 0; mi < 4; mi++)
#pragma unroll
        for (int nf = 0; nf < 2; nf++)
#pragma unroll
            for (int r = 0; r < 4; r++)
                Fw[(mi * 16 + r0 + r) * FPAD + nf * 16 + ln] = f2b(sval[mi][nf][r]);
    __syncthreads();

    // ---- field_new = fe + S @ wout + bout ----
    bf16x8 SA[4];
#pragma unroll
    for (int mi = 0; mi < 4; mi++) SA[mi] = ldsfrag(&Fw[(mi * 16 + ln) * FPAD + kq]);
#pragma unroll
    for (int mi = 0; mi < 4; mi++) {
#pragma unroll
        for (int nf = 0; nf < 2; nf++) {
            f32x4 oc = __builtin_amdgcn_mfma_f32_16x16x32_bf16(SA[mi], woutf[nf], zero, 0, 0, 0);
            float fnew[4];
#pragma unroll
            for (int r = 0; r < 4; r++) {
                fnew[r] = fe[mi][nf][r] + oc[r] + bov[nf];
                const size_t idx = (size_t)(mw + mi * 16 + r0 + r) * FD + nf * 16 + ln;
                field[idx] = fnew[r];
                state[idx] = f2b(sval[mi][nf][r]);
            }
            ushort4 pk = {f2b(fnew[0]), f2b(fnew[1]), f2b(fnew[2]), f2b(fnew[3])};
            const size_t ft_addr = (size_t)(b * FD + nf * 16 + ln) * NNODE + n0 + mi * 16 + r0;
            *(ushort4*)&fT[ft_addr] = pk;
        }
    }
}

// ---------------- decoder ------------------------------------------------------------
__global__ __launch_bounds__(256, 2) void decoder(const float* __restrict__ field,
                                                  const float* __restrict__ dw1,
                                                  const float* __restrict__ db1,
                                                  const float* __restrict__ dw2,
                                                  const float* __restrict__ db2,
                                                  float* __restrict__ out) {
    const int gid = blockIdx.x * 256 + threadIdx.x;
    const int b = gid >> 12;
    const int n = gid & (NNODE - 1);
    float ff[FD];
#pragma unroll
    for (int o4 = 0; o4 < FD / 4; o4++) {
        float4 v = *(const float4*)&field[(size_t)gid * FD + o4 * 4];
        ff[o4 * 4 + 0] = v.x; ff[o4 * 4 + 1] = v.y; ff[o4 * 4 + 2] = v.z; ff[o4 * 4 + 3] = v.w;
    }
    float o[OUTD];
#pragma unroll
    for (int t = 0; t < OUTD; t++) o[t] = db2[t];
    for (int j = 0; j < HD; j++) {
        float h = db1[j];
#pragma unroll
        for (int k = 0; k < FD; k++) h += ff[k] * dw1[k * HD + j];
        h = fmaxf(h, 0.f);
#pragma unroll
        for (int t = 0; t < OUTD; t++) o[t] += h * dw2[j * OUTD + t];
    }
#pragma unroll
    for (int t = 0; t < OUTD; t++)
        out[(size_t)(b * OUTD + t) * NNODE + n] = o[t];
}

extern "C" void kernel_launch(void* const* d_in, const int* in_sizes, int n_in,
                              void* d_out, int out_size, void* d_ws, size_t ws_size,
                              hipStream_t stream) {
    (void)in_sizes; (void)n_in; (void)out_size; (void)ws_size;
    const float* hist    = (const float*)d_in[0];
    const float* tid_emb = (const float*)d_in[5];
    const float* diw_emb = (const float*)d_in[6];
    const float* t2f_w   = (const float*)d_in[7];
    const float* t2f_b   = (const float*)d_in[8];
    const float* enc_w1  = (const float*)d_in[9];
    const float* enc_b1  = (const float*)d_in[10];
    const float* enc_w2  = (const float*)d_in[11];
    const float* enc_b2  = (const float*)d_in[12];
    const float* node_emb= (const float*)d_in[13];
    const float* pde_w1  = (const float*)d_in[14];
    const float* pde_b1  = (const float*)d_in[15];
    const float* pde_w2  = (const float*)d_in[16];
    const float* pde_b2  = (const float*)d_in[17];
    const float* ss_win  = (const float*)d_in[18];
    const float* ss_wst  = (const float*)d_in[19];
    const float* ss_b    = (const float*)d_in[20];
    const float* ss_wout = (const float*)d_in[21];
    const float* ss_bout = (const float*)d_in[22];
    const float* dec_w1  = (const float*)d_in[23];
    const float* dec_b1  = (const float*)d_in[24];
    const float* dec_w2  = (const float*)d_in[25];
    const float* dec_b2  = (const float*)d_in[26];
    const float* pde_mix = (const float*)d_in[27];

    char* w = (char*)d_ws;
    unsigned short* A_bf = (unsigned short*)w;  w += (size_t)KDIM * KDIM * 2;   // 33.5 MB
    unsigned short* fT   = (unsigned short*)w;  w += (size_t)MROWS * KDIM * 2;  // 16.8 MB
    float* field = (float*)w;                   w += (size_t)MTOT * FD * 4;     // 33.5 MB
    unsigned short* state = (unsigned short*)w; w += (size_t)MTOT * FD * 2;     // 16.8 MB
    unsigned short* Cp    = (unsigned short*)w; w += (size_t)2 * MTOT * FD * 2; // 33.5 MB (2 halves)

    build_A<<<NNODE, 256, 0, stream>>>(node_emb, A_bf);
    encoder<<<(BATCH * NNODE) / 256, 256, 0, stream>>>(hist, tid_emb, diw_emb, t2f_w,
                                                       t2f_b, enc_w1, enc_b1, enc_w2,
                                                       enc_b2, field, fT);
    for (int s = 0; s < 4; s++) {
        gemm_bt<<<dim3(16, 32, 2), 256, 0, stream>>>(fT, A_bf, Cp);
        step_mfma<<<MTOT / 256, 256, 0, stream>>>(
            Cp, Cp + (size_t)MTOT * FD, field, state, fT, pde_w1, pde_b1, pde_w2,
            pde_b2, ss_win, ss_wst, ss_b, ss_wout, ss_bout, pde_mix, s == 0 ? 1 : 0);
    }
    decoder<<<(BATCH * NNODE) / 256, 256, 0, stream>>>(field, dec_w1, dec_b1, dec_w2,
                                                       dec_b2, (float*)d_out);
}

// Round 5
// 731.965 us; speedup vs baseline: 2.8919x; 1.0518x over previous
//
#include <hip/hip_runtime.h>

#define BATCH 64
#define LHIST 12
#define NNODE 4096
#define CCH   3
#define FD    32
#define HD    64
#define OUTD  12
#define TIDN  288
#define DIWN  7
#define TDD   16
#define EMBD  10
#define MROWS 2048   // BATCH*FD  (gemm M)
#define KDIM  4096   // nodes
#define MTOT  (BATCH * NNODE)

typedef __attribute__((ext_vector_type(8))) short bf16x8;
typedef __attribute__((ext_vector_type(4))) float f32x4;

union BF8U { bf16x8 v; unsigned short s[8]; };

__device__ __forceinline__ unsigned short f2b(float f) {
    union { float f; unsigned u; } v; v.f = f;
    unsigned r = v.u + 0x7fffu + ((v.u >> 16) & 1u);
    return (unsigned short)(r >> 16);
}

__device__ __forceinline__ float b2f(unsigned short u) {
    union { unsigned u; float f; } v; v.u = (unsigned)u << 16; return v.f;
}

__device__ __forceinline__ float fast_tanh(float x) {
    x = fminf(fmaxf(x, -15.f), 15.f);
    const float e = __expf(2.f * x);
    return (e - 1.f) / (e + 1.f);
}

__device__ __forceinline__ bf16x8 ldsfrag(const unsigned short* p) {
    return *(const bf16x8*)p;
}

__device__ __forceinline__ bf16x8 pack8(float4 a, float4 b) {
    BF8U u;
    u.s[0] = f2b(a.x); u.s[1] = f2b(a.y); u.s[2] = f2b(a.z); u.s[3] = f2b(a.w);
    u.s[4] = f2b(b.x); u.s[5] = f2b(b.y); u.s[6] = f2b(b.z); u.s[7] = f2b(b.w);
    return u.v;
}

// ---------------- A = softmax(relu(emb @ emb^T), axis=-1), stored bf16 row-major ----
__global__ __launch_bounds__(256) void build_A(const float* __restrict__ emb,
                                               unsigned short* __restrict__ A) {
    const int n = blockIdx.x;
    const int tid = threadIdx.x;
    __shared__ float sc[NNODE];
    __shared__ float red[256];
    float e[EMBD];
#pragma unroll
    for (int c = 0; c < EMBD; c++) e[c] = emb[(size_t)n * EMBD + c];
    float mx = 0.f;
    for (int m = tid; m < NNODE; m += 256) {
        float s = 0.f;
#pragma unroll
        for (int c = 0; c < EMBD; c++) s += e[c] * emb[(size_t)m * EMBD + c];
        s = fmaxf(s, 0.f);
        sc[m] = s;
        mx = fmaxf(mx, s);
    }
    red[tid] = mx;
    __syncthreads();
    for (int off = 128; off > 0; off >>= 1) {
        if (tid < off) red[tid] = fmaxf(red[tid], red[tid + off]);
        __syncthreads();
    }
    mx = red[0];
    __syncthreads();
    float sum = 0.f;
    for (int m = tid; m < NNODE; m += 256) {
        float v = expf(sc[m] - mx);
        sc[m] = v;
        sum += v;
    }
    red[tid] = sum;
    __syncthreads();
    for (int off = 128; off > 0; off >>= 1) {
        if (tid < off) red[tid] += red[tid + off];
        __syncthreads();
    }
    const float inv = 1.f / red[0];
    for (int m = tid; m < NNODE; m += 256)
        A[(size_t)n * NNODE + m] = f2b(sc[m] * inv);
}

// ---------------- encoder: field[(b,n)][f] fp32 + fT[(b,f)][n] bf16 ------------------
__global__ __launch_bounds__(256, 2) void encoder(const float* __restrict__ hist,
                                                  const float* __restrict__ tid_emb,
                                                  const float* __restrict__ diw_emb,
                                                  const float* __restrict__ t2f_w,
                                                  const float* __restrict__ t2f_b,
                                                  const float* __restrict__ enc_w1,
                                                  const float* __restrict__ enc_b1,
                                                  const float* __restrict__ enc_w2,
                                                  const float* __restrict__ enc_b2,
                                                  float* __restrict__ field,
                                                  unsigned short* __restrict__ fT) {
    const int gid = blockIdx.x * 256 + threadIdx.x;
    const int b = gid >> 12;
    const int n = gid & (NNODE - 1);
    const float* hb = hist + ((size_t)b * LHIST * NNODE + n) * CCH;
    float x[LHIST * CCH];
#pragma unroll
    for (int l = 0; l < LHIST; l++) {
        x[l * 3 + 0] = hb[(size_t)l * NNODE * CCH + 0];
        x[l * 3 + 1] = hb[(size_t)l * NNODE * CCH + 1];
        x[l * 3 + 2] = hb[(size_t)l * NNODE * CCH + 2];
    }
    float f[FD];
#pragma unroll
    for (int o = 0; o < FD; o++) f[o] = enc_b2[o] + t2f_b[o];
    for (int j = 0; j < HD; j++) {
        float h = enc_b1[j];
#pragma unroll
        for (int k = 0; k < LHIST * CCH; k++) h += x[k] * enc_w1[k * HD + j];
        h = fmaxf(h, 0.f);
#pragma unroll
        for (int o = 0; o < FD; o++) f[o] += h * enc_w2[j * FD + o];
    }
    const int ti = min(max((int)(x[11 * 3 + 1] * 288.0f), 0), TIDN - 1);
    const int di = min(max((int)(x[11 * 3 + 2] * 7.0f), 0), DIWN - 1);
    for (int g = 0; g < TDD; g++) {
        const float tg = tid_emb[ti * TDD + g];
        const float dg = diw_emb[di * TDD + g];
#pragma unroll
        for (int o = 0; o < FD; o++)
            f[o] += tg * t2f_w[g * FD + o] + dg * t2f_w[(TDD + g) * FD + o];
    }
#pragma unroll
    for (int o4 = 0; o4 < FD / 4; o4++) {
        float4 v = {f[o4 * 4 + 0], f[o4 * 4 + 1], f[o4 * 4 + 2], f[o4 * 4 + 3]};
        *(float4*)&field[(size_t)gid * FD + o4 * 4] = v;
    }
#pragma unroll
    for (int o = 0; o < FD; o++)
        fT[(size_t)(b * FD + o) * NNODE + n] = f2b(f[o]);
}

// ---------------- split-K GEMM, reg-prefetch double-buffer pipeline ------------------
// Loads for tile t+1 -> VGPRs, compute tile t from LDS (covers latency), then
// ds_write regs -> other buffer (compiler's vmcnt wait lands AFTER compute),
// __syncthreads is then cheap. XOR bank-swizzle on the write side (read kq as R4).
__global__ __launch_bounds__(256) void gemm_bt(const unsigned short* __restrict__ X,
                                               const unsigned short* __restrict__ Y,
                                               unsigned short* __restrict__ Cp) {
    constexpr int K = KDIM;
    constexpr int KS = KDIM / 2;
    constexpr int BK = 32;
    __shared__ __align__(16) unsigned short Xs[2][128 * BK];
    __shared__ __align__(16) unsigned short Ys[2][128 * BK];
    const int tid = threadIdx.x;
    const int wave = tid >> 6;
    const int lane = tid & 63;

    // XCD-aware remap: each XCD owns 4 consecutive j-tiles (A rows), streams i.
    const int l = blockIdx.x + 16 * blockIdx.y;   // 0..511
    const int xcd = l & 7;
    const int rem = l >> 3;
    const int by = xcd * 4 + (rem & 3);
    const int bx = rem >> 2;
    const int i0 = bx * 128;
    const int j0 = by * 128;
    const int k0 = blockIdx.z * KS;
    unsigned short* C = Cp + (size_t)blockIdx.z * MTOT * FD;

    const int wi = (wave >> 1) * 64;
    const int wj = (wave & 1) * 64;

    const int lrow = lane >> 2;                                  // 0..15
    const int gcol = (lane & 3) * 8;                             // linear global chunk
    const int scol = ((lane & 3) ^ ((lane >> 3) & 3)) * 8;       // swizzled LDS chunk

    const unsigned short* Xg = X + (size_t)(i0 + wave * 32 + lrow) * K + k0 + gcol;
    const unsigned short* Yg = Y + (size_t)(j0 + wave * 32 + lrow) * K + k0 + gcol;
    const int ldoff0 = (wave * 32 + lrow) * BK + scol;
    const int ldoff1 = (wave * 32 + 16 + lrow) * BK + scol;

    const f32x4 zero = {0.f, 0.f, 0.f, 0.f};
    f32x4 acc[4][4];
#pragma unroll
    for (int a = 0; a < 4; a++)
#pragma unroll
        for (int b = 0; b < 4; b++) acc[a][b] = zero;

    const int fr = lane & 15;
    const int q = lane >> 4;
    const int kq = (q ^ ((fr >> 1) & 3)) * 8;     // de-swizzled frag chunk

    // prologue: tile 0 -> regs -> buf 0
    uint4 rx0 = *(const uint4*)(Xg);
    uint4 rx1 = *(const uint4*)(Xg + 16 * K);
    uint4 ry0 = *(const uint4*)(Yg);
    uint4 ry1 = *(const uint4*)(Yg + 16 * K);
    *(uint4*)&Xs[0][ldoff0] = rx0;
    *(uint4*)&Xs[0][ldoff1] = rx1;
    *(uint4*)&Ys[0][ldoff0] = ry0;
    *(uint4*)&Ys[0][ldoff1] = ry1;
    __syncthreads();

    int p = 0;
    for (int kt = 0; kt < KS; kt += BK) {
        const bool more = (kt + BK < KS);
        if (more) {
            rx0 = *(const uint4*)(Xg + kt + BK);
            rx1 = *(const uint4*)(Xg + kt + BK + 16 * K);
            ry0 = *(const uint4*)(Yg + kt + BK);
            ry1 = *(const uint4*)(Yg + kt + BK + 16 * K);
        }
        bf16x8 fa[4], fb[4];
#pragma unroll
        for (int t = 0; t < 4; t++)
            fa[t] = *(const bf16x8*)&Xs[p][(wi + t * 16 + fr) * BK + kq];
#pragma unroll
        for (int t = 0; t < 4; t++)
            fb[t] = *(const bf16x8*)&Ys[p][(wj + t * 16 + fr) * BK + kq];
#pragma unroll
        for (int mi = 0; mi < 4; mi++)
#pragma unroll
            for (int ni = 0; ni < 4; ni++)
                acc[mi][ni] = __builtin_amdgcn_mfma_f32_16x16x32_bf16(
                    fa[mi], fb[ni], acc[mi][ni], 0, 0, 0);
        if (more) {
            const int np = p ^ 1;
            *(uint4*)&Xs[np][ldoff0] = rx0;
            *(uint4*)&Xs[np][ldoff1] = rx1;
            *(uint4*)&Ys[np][ldoff0] = ry0;
            *(uint4*)&Ys[np][ldoff1] = ry1;
            __syncthreads();
            p = np;
        }
    }

    // epilogue: row=(b,f) col=n  ->  bf16 partial at [((b*4096)+col)*32 + f]
    const int r0 = q * 4;
#pragma unroll
    for (int mi = 0; mi < 4; mi++) {
#pragma unroll
        for (int ni = 0; ni < 4; ni++) {
            const int R0 = i0 + wi + mi * 16 + r0;
            const int col = j0 + wj + ni * 16 + fr;
            const size_t addr = ((size_t)(R0 >> 5) * NNODE + col) * FD + (R0 & 31);
            ushort4 pk = {f2b(acc[mi][ni][0]), f2b(acc[mi][ni][1]),
                          f2b(acc[mi][ni][2]), f2b(acc[mi][ni][3])};
            *(ushort4*)&C[addr] = pk;
        }
    }
}

// ---------------- fused MFMA step (+ decoder on last step) ---------------------------
// Hw/Fw are PER-WAVE LDS tiles: same-wave DS ops are program-ordered, so no
// __syncthreads between phases (only after block-wide weight staging).
#define HPAD 72
#define FPAD 40
__global__ __launch_bounds__(256, 2) void step_mfma(const unsigned short* __restrict__ Ct0,
                                                    const unsigned short* __restrict__ Ct1,
                                                    float* __restrict__ field,
                                                    unsigned short* __restrict__ state,
                                                    unsigned short* __restrict__ fT,
                                                    const float* __restrict__ pde_w1,
                                                    const float* __restrict__ pde_b1,
                                                    const float* __restrict__ pde_w2,
                                                    const float* __restrict__ pde_b2,
                                                    const float* __restrict__ ss_win,
                                                    const float* __restrict__ ss_wst,
                                                    const float* __restrict__ ss_b,
                                                    const float* __restrict__ ss_wout,
                                                    const float* __restrict__ ss_bout,
                                                    const float* __restrict__ pde_mix,
                                                    const float* __restrict__ dec_w1,
                                                    const float* __restrict__ dec_b1,
                                                    const float* __restrict__ dec_w2,
                                                    const float* __restrict__ dec_b2,
                                                    float* __restrict__ out,
                                                    int first, int last) {
    __shared__ __align__(16) unsigned short W1T[HD * FD];
    __shared__ __align__(16) unsigned short W2T[FD * HD];
    __shared__ __align__(16) unsigned short WinT[FD * FD];
    __shared__ __align__(16) unsigned short WstT[FD * FD];
    __shared__ __align__(16) unsigned short WoutT[FD * FD];
    __shared__ __align__(16) unsigned short Wd1T[HD * FD];
    __shared__ __align__(16) unsigned short Wd2T[16 * HD];
    __shared__ __align__(16) unsigned short Hs[4 * 64 * HPAD];
    __shared__ __align__(16) unsigned short Fs[4 * 64 * FPAD];

    const int tid = threadIdx.x;
    for (int i = tid; i < HD * FD; i += 256) W1T[(i & 63) * FD + (i >> 6)] = f2b(pde_w1[i]);
    for (int i = tid; i < HD * FD; i += 256) W2T[(i & 31) * HD + (i >> 5)] = f2b(pde_w2[i]);
    for (int i = tid; i < FD * FD; i += 256) {
        WinT [(i & 31) * FD + (i >> 5)] = f2b(ss_win[i]);
        WstT [(i & 31) * FD + (i >> 5)] = f2b(ss_wst[i]);
        WoutT[(i & 31) * FD + (i >> 5)] = f2b(ss_wout[i]);
    }
    if (last) {
        for (int i = tid; i < HD * FD; i += 256)
            Wd1T[(i & 63) * FD + (i >> 6)] = f2b(dec_w1[i]);
        for (int i = tid; i < 16 * HD; i += 256) {
            const int o = i >> 6, j = i & 63;
            Wd2T[i] = (o < OUTD) ? f2b(dec_w2[j * OUTD + o]) : (unsigned short)0;
        }
    }
    __syncthreads();

    const int wv = tid >> 6;
    const int lane = tid & 63;
    const int ln = lane & 15;
    const int q = lane >> 4;
    const int kq = q * 8;
    const int r0 = q * 4;
    const int mw = blockIdx.x * 256 + wv * 64;
    const int b = mw >> 12;
    const int n0 = mw & (NNODE - 1);
    unsigned short* Hw = &Hs[wv * 64 * HPAD];
    unsigned short* Fw = &Fs[wv * 64 * FPAD];

    const float alpha = 1.f / (1.f + __expf(-pde_mix[0]));
    const float dt = 0.25f;

    bf16x8 w1f[4], w2f[2][2], winf[2], wstf[2], woutf[2];
#pragma unroll
    for (int nj = 0; nj < 4; nj++) w1f[nj] = ldsfrag(&W1T[(nj * 16 + ln) * FD + kq]);
#pragma unroll
    for (int nf = 0; nf < 2; nf++) {
#pragma unroll
        for (int kk = 0; kk < 2; kk++)
            w2f[nf][kk] = ldsfrag(&W2T[(nf * 16 + ln) * HD + kk * 32 + kq]);
        winf[nf]  = ldsfrag(&WinT [(nf * 16 + ln) * FD + kq]);
        wstf[nf]  = ldsfrag(&WstT [(nf * 16 + ln) * FD + kq]);
        woutf[nf] = ldsfrag(&WoutT[(nf * 16 + ln) * FD + kq]);
    }

    float b1v[4], b2v[2], bsv[2], bov[2];
#pragma unroll
    for (int nj = 0; nj < 4; nj++) b1v[nj] = pde_b1[nj * 16 + ln];
#pragma unroll
    for (int nf = 0; nf < 2; nf++) {
        b2v[nf] = pde_b2[nf * 16 + ln];
        bsv[nf] = ss_b[nf * 16 + ln];
        bov[nf] = ss_bout[nf * 16 + ln];
    }

    bf16x8 fA[4], stA[4];
#pragma unroll
    for (int mi = 0; mi < 4; mi++) {
        const float4* fp = (const float4*)&field[(size_t)(mw + mi * 16 + ln) * FD + kq];
        fA[mi] = pack8(fp[0], fp[1]);
    }
    if (!first) {
#pragma unroll
        for (int mi = 0; mi < 4; mi++)
            stA[mi] = *(const bf16x8*)&state[(size_t)(mw + mi * 16 + ln) * FD + kq];
    }

    const f32x4 zero = {0.f, 0.f, 0.f, 0.f};

    // ---- H = relu(field @ w1 + b1) ----
    f32x4 hc[4][4];
#pragma unroll
    for (int mi = 0; mi < 4; mi++)
#pragma unroll
        for (int nj = 0; nj < 4; nj++)
            hc[mi][nj] = __builtin_amdgcn_mfma_f32_16x16x32_bf16(fA[mi], w1f[nj], zero, 0, 0, 0);
#pragma unroll
    for (int mi = 0; mi < 4; mi++)
#pragma unroll
        for (int nj = 0; nj < 4; nj++)
#pragma unroll
            for (int r = 0; r < 4; r++)
                Hw[(mi * 16 + r0 + r) * HPAD + nj * 16 + ln] =
                    f2b(fmaxf(hc[mi][nj][r] + b1v[nj], 0.f));

    // ---- field & Ct (=Ct0+Ct1) in C-layout ----
    float fld[4][2][4], ctv[4][2][4];
#pragma unroll
    for (int mi = 0; mi < 4; mi++)
#pragma unroll
        for (int nf = 0; nf < 2; nf++)
#pragma unroll
            for (int r = 0; r < 4; r++) {
                const size_t idx = (size_t)(mw + mi * 16 + r0 + r) * FD + nf * 16 + ln;
                fld[mi][nf][r] = field[idx];
                ctv[mi][nf][r] = b2f(Ct0[idx]) + b2f(Ct1[idx]);
            }

    // ---- N_F = H @ w2 + b2 ----
    bf16x8 hA[4][2];
#pragma unroll
    for (int mi = 0; mi < 4; mi++)
#pragma unroll
        for (int kk = 0; kk < 2; kk++)
            hA[mi][kk] = ldsfrag(&Hw[(mi * 16 + ln) * HPAD + kk * 32 + kq]);
    f32x4 nc[4][2];
#pragma unroll
    for (int mi = 0; mi < 4; mi++)
#pragma unroll
        for (int nf = 0; nf < 2; nf++) {
            f32x4 a = __builtin_amdgcn_mfma_f32_16x16x32_bf16(hA[mi][0], w2f[nf][0], zero, 0, 0, 0);
            nc[mi][nf] = __builtin_amdgcn_mfma_f32_16x16x32_bf16(hA[mi][1], w2f[nf][1], a, 0, 0, 0);
        }

    // ---- fe ----
    float fe[4][2][4];
#pragma unroll
    for (int mi = 0; mi < 4; mi++)
#pragma unroll
        for (int nf = 0; nf < 2; nf++)
#pragma unroll
            for (int r = 0; r < 4; r++) {
                const float nfv = nc[mi][nf][r] + b2v[nf];
                const float fv = fld[mi][nf][r];
                fe[mi][nf][r] = fv + (alpha * (ctv[mi][nf][r] - fv) + (1.f - alpha) * nfv) * dt;
                Fw[(mi * 16 + r0 + r) * FPAD + nf * 16 + ln] = f2b(fe[mi][nf][r]);
            }

    // ---- S = tanh(fe @ win + st @ wst + b) ----
    bf16x8 feA[4];
#pragma unroll
    for (int mi = 0; mi < 4; mi++) feA[mi] = ldsfrag(&Fw[(mi * 16 + ln) * FPAD + kq]);
    f32x4 sc_[4][2];
#pragma unroll
    for (int mi = 0; mi < 4; mi++)
#pragma unroll
        for (int nf = 0; nf < 2; nf++) {
            f32x4 a = __builtin_amdgcn_mfma_f32_16x16x32_bf16(feA[mi], winf[nf], zero, 0, 0, 0);
            if (!first)
                a = __builtin_amdgcn_mfma_f32_16x16x32_bf16(stA[mi], wstf[nf], a, 0, 0, 0);
            sc_[mi][nf] = a;
        }
    float sval[4][2][4];
#pragma unroll
    for (int mi = 0; mi < 4; mi++)
#pragma unroll
        for (int nf = 0; nf < 2; nf++)
#pragma unroll
            for (int r = 0; r < 4; r++)
                sval[mi][nf][r] = fast_tanh(sc_[mi][nf][r] + bsv[nf]);
#pragma unroll
    for (int mi = 0; mi < 4; mi++)
#pragma unroll
        for (int nf = 0; nf < 2; nf++)
#pragma unroll
            for (int r = 0; r < 4; r++)
                Fw[(mi * 16 + r0 + r) * FPAD + nf * 16 + ln] = f2b(sval[mi][nf][r]);

    // ---- field_new = fe + S @ wout + bout ----
    bf16x8 SA[4];
#pragma unroll
    for (int mi = 0; mi < 4; mi++) SA[mi] = ldsfrag(&Fw[(mi * 16 + ln) * FPAD + kq]);
    float fnew[4][2][4];
#pragma unroll
    for (int mi = 0; mi < 4; mi++)
#pragma unroll
        for (int nf = 0; nf < 2; nf++) {
            f32x4 oc = __builtin_amdgcn_mfma_f32_16x16x32_bf16(SA[mi], woutf[nf], zero, 0, 0, 0);
#pragma unroll
            for (int r = 0; r < 4; r++)
                fnew[mi][nf][r] = fe[mi][nf][r] + oc[r] + bov[nf];
        }

    if (!last) {
#pragma unroll
        for (int mi = 0; mi < 4; mi++) {
#pragma unroll
            for (int nf = 0; nf < 2; nf++) {
#pragma unroll
                for (int r = 0; r < 4; r++) {
                    const size_t idx = (size_t)(mw + mi * 16 + r0 + r) * FD + nf * 16 + ln;
                    field[idx] = fnew[mi][nf][r];
                    state[idx] = f2b(sval[mi][nf][r]);
                }
                ushort4 pk = {f2b(fnew[mi][nf][0]), f2b(fnew[mi][nf][1]),
                              f2b(fnew[mi][nf][2]), f2b(fnew[mi][nf][3])};
                const size_t ft_addr = (size_t)(b * FD + nf * 16 + ln) * NNODE + n0 + mi * 16 + r0;
                *(ushort4*)&fT[ft_addr] = pk;
            }
        }
    } else {
        // ---- fused decoder: out[b][o][n] = relu(fnew @ dw1 + db1) @ dw2 + db2 ----
        bf16x8 wd1f[4], wd2f[2];
#pragma unroll
        for (int nj = 0; nj < 4; nj++) wd1f[nj] = ldsfrag(&Wd1T[(nj * 16 + ln) * FD + kq]);
#pragma unroll
        for (int kk = 0; kk < 2; kk++) wd2f[kk] = ldsfrag(&Wd2T[ln * HD + kk * 32 + kq]);
        float db1v[4];
#pragma unroll
        for (int nj = 0; nj < 4; nj++) db1v[nj] = dec_b1[nj * 16 + ln];
        const float db2v = (ln < OUTD) ? dec_b2[ln] : 0.f;

        // fnew -> Fw (bf16) -> A-frags
#pragma unroll
        for (int mi = 0; mi < 4; mi++)
#pragma unroll
            for (int nf = 0; nf < 2; nf++)
#pragma unroll
                for (int r = 0; r < 4; r++)
                    Fw[(mi * 16 + r0 + r) * FPAD + nf * 16 + ln] = f2b(fnew[mi][nf][r]);
        bf16x8 fnA[4];
#pragma unroll
        for (int mi = 0; mi < 4; mi++) fnA[mi] = ldsfrag(&Fw[(mi * 16 + ln) * FPAD + kq]);

        // H2 = relu(fnew @ dw1 + db1)
        f32x4 h2[4][4];
#pragma unroll
        for (int mi = 0; mi < 4; mi++)
#pragma unroll
            for (int nj = 0; nj < 4; nj++)
                h2[mi][nj] = __builtin_amdgcn_mfma_f32_16x16x32_bf16(fnA[mi], wd1f[nj], zero, 0, 0, 0);
#pragma unroll
        for (int mi = 0; mi < 4; mi++)
#pragma unroll
            for (int nj = 0; nj < 4; nj++)
#pragma unroll
                for (int r = 0; r < 4; r++)
                    Hw[(mi * 16 + r0 + r) * HPAD + nj * 16 + ln] =
                        f2b(fmaxf(h2[mi][nj][r] + db1v[nj], 0.f));
        bf16x8 h2A[4][2];
#pragma unroll
        for (int mi = 0; mi < 4; mi++)
#pragma unroll
            for (int kk = 0; kk < 2; kk++)
                h2A[mi][kk] = ldsfrag(&Hw[(mi * 16 + ln) * HPAD + kk * 32 + kq]);
#pragma unroll
        for (int mi = 0; mi < 4; mi++) {
            f32x4 a = __builtin_amdgcn_mfma_f32_16x16x32_bf16(h2A[mi][0], wd2f[0], zero, 0, 0, 0);
            a = __builtin_amdgcn_mfma_f32_16x16x32_bf16(h2A[mi][1], wd2f[1], a, 0, 0, 0);
            if (ln < OUTD) {
                float4 v = {a[0] + db2v, a[1] + db2v, a[2] + db2v, a[3] + db2v};
                *(float4*)&out[(size_t)(b * OUTD + ln) * NNODE + n0 + mi * 16 + r0] = v;
            }
        }
    }
}

extern "C" void kernel_launch(void* const* d_in, const int* in_sizes, int n_in,
                              void* d_out, int out_size, void* d_ws, size_t ws_size,
                              hipStream_t stream) {
    (void)in_sizes; (void)n_in; (void)out_size; (void)ws_size;
    const float* hist    = (const float*)d_in[0];
    const float* tid_emb = (const float*)d_in[5];
    const float* diw_emb = (const float*)d_in[6];
    const float* t2f_w   = (const float*)d_in[7];
    const float* t2f_b   = (const float*)d_in[8];
    const float* enc_w1  = (const float*)d_in[9];
    const float* enc_b1  = (const float*)d_in[10];
    const float* enc_w2  = (const float*)d_in[11];
    const float* enc_b2  = (const float*)d_in[12];
    const float* node_emb= (const float*)d_in[13];
    const float* pde_w1  = (const float*)d_in[14];
    const float* pde_b1  = (const float*)d_in[15];
    const float* pde_w2  = (const float*)d_in[16];
    const float* pde_b2  = (const float*)d_in[17];
    const float* ss_win  = (const float*)d_in[18];
    const float* ss_wst  = (const float*)d_in[19];
    const float* ss_b    = (const float*)d_in[20];
    const float* ss_wout = (const float*)d_in[21];
    const float* ss_bout = (const float*)d_in[22];
    const float* dec_w1  = (const float*)d_in[23];
    const float* dec_b1  = (const float*)d_in[24];
    const float* dec_w2  = (const float*)d_in[25];
    const float* dec_b2  = (const float*)d_in[26];
    const float* pde_mix = (const float*)d_in[27];

    char* w = (char*)d_ws;
    unsigned short* A_bf = (unsigned short*)w;  w += (size_t)KDIM * KDIM * 2;   // 33.5 MB
    unsigned short* fT   = (unsigned short*)w;  w += (size_t)MROWS * KDIM * 2;  // 16.8 MB
    float* field = (float*)w;                   w += (size_t)MTOT * FD * 4;     // 33.5 MB
    unsigned short* state = (unsigned short*)w; w += (size_t)MTOT * FD * 2;     // 16.8 MB
    unsigned short* Cp    = (unsigned short*)w; w += (size_t)2 * MTOT * FD * 2; // 33.5 MB

    build_A<<<NNODE, 256, 0, stream>>>(node_emb, A_bf);
    encoder<<<(BATCH * NNODE) / 256, 256, 0, stream>>>(hist, tid_emb, diw_emb, t2f_w,
                                                       t2f_b, enc_w1, enc_b1, enc_w2,
                                                       enc_b2, field, fT);
    for (int s = 0; s < 4; s++) {
        gemm_bt<<<dim3(16, 32, 2), 256, 0, stream>>>(fT, A_bf, Cp);
        step_mfma<<<MTOT / 256, 256, 0, stream>>>(
            Cp, Cp + (size_t)MTOT * FD, field, state, fT, pde_w1, pde_b1, pde_w2,
            pde_b2, ss_win, ss_wst, ss_b, ss_wout, ss_bout, pde_mix,
            dec_w1, dec_b1, dec_w2, dec_b2, (float*)d_out,
            s == 0 ? 1 : 0, s == 3 ? 1 : 0);
    }
}

// Round 6
// 683.485 us; speedup vs baseline: 3.0970x; 1.0709x over previous
//
#include <hip/hip_runtime.h>

#define BATCH 64
#define LHIST 12
#define NNODE 4096
#define CCH   3
#define FD    32
#define HD    64
#define OUTD  12
#define TIDN  288
#define DIWN  7
#define TDD   16
#define EMBD  10
#define MROWS 2048
#define KDIM  4096
#define MTOT  (BATCH * NNODE)

typedef __attribute__((ext_vector_type(8))) short bf16x8;
typedef __attribute__((ext_vector_type(4))) float f32x4;

union BF8U { bf16x8 v; unsigned short s[8]; };

__device__ __forceinline__ unsigned short f2b(float f) {
    union { float f; unsigned u; } v; v.f = f;
    unsigned r = v.u + 0x7fffu + ((v.u >> 16) & 1u);
    return (unsigned short)(r >> 16);
}

__device__ __forceinline__ float b2f(unsigned short u) {
    union { unsigned u; float f; } v; v.u = (unsigned)u << 16; return v.f;
}

__device__ __forceinline__ float fast_tanh(float x) {
    x = fminf(fmaxf(x, -15.f), 15.f);
    const float e = __expf(2.f * x);
    return (e - 1.f) / (e + 1.f);
}

__device__ __forceinline__ bf16x8 ldsfrag(const unsigned short* p) {
    return *(const bf16x8*)p;
}

__device__ __forceinline__ bf16x8 pack8(float4 a, float4 b) {
    BF8U u;
    u.s[0] = f2b(a.x); u.s[1] = f2b(a.y); u.s[2] = f2b(a.z); u.s[3] = f2b(a.w);
    u.s[4] = f2b(b.x); u.s[5] = f2b(b.y); u.s[6] = f2b(b.z); u.s[7] = f2b(b.w);
    return u.v;
}

// ---------------- A = softmax(relu(emb @ emb^T)) bf16 row-major ----------------------
__global__ __launch_bounds__(256) void build_A(const float* __restrict__ emb,
                                               unsigned short* __restrict__ A) {
    const int n = blockIdx.x;
    const int tid = threadIdx.x;
    __shared__ float sc[NNODE];
    __shared__ float red[256];
    float e[EMBD];
#pragma unroll
    for (int c = 0; c < EMBD; c++) e[c] = emb[(size_t)n * EMBD + c];
    float mx = 0.f;
    for (int m = tid; m < NNODE; m += 256) {
        float s = 0.f;
#pragma unroll
        for (int c = 0; c < EMBD; c++) s += e[c] * emb[(size_t)m * EMBD + c];
        s = fmaxf(s, 0.f);
        sc[m] = s;
        mx = fmaxf(mx, s);
    }
    red[tid] = mx;
    __syncthreads();
    for (int off = 128; off > 0; off >>= 1) {
        if (tid < off) red[tid] = fmaxf(red[tid], red[tid + off]);
        __syncthreads();
    }
    mx = red[0];
    __syncthreads();
    float sum = 0.f;
    for (int m = tid; m < NNODE; m += 256) {
        float v = expf(sc[m] - mx);
        sc[m] = v;
        sum += v;
    }
    red[tid] = sum;
    __syncthreads();
    for (int off = 128; off > 0; off >>= 1) {
        if (tid < off) red[tid] += red[tid + off];
        __syncthreads();
    }
    const float inv = 1.f / red[0];
    for (int m = tid; m < NNODE; m += 256)
        A[(size_t)n * NNODE + m] = f2b(sc[m] * inv);
}

// ---------------- encoder ------------------------------------------------------------
__global__ __launch_bounds__(256, 2) void encoder(const float* __restrict__ hist,
                                                  const float* __restrict__ tid_emb,
                                                  const float* __restrict__ diw_emb,
                                                  const float* __restrict__ t2f_w,
                                                  const float* __restrict__ t2f_b,
                                                  const float* __restrict__ enc_w1,
                                                  const float* __restrict__ enc_b1,
                                                  const float* __restrict__ enc_w2,
                                                  const float* __restrict__ enc_b2,
                                                  float* __restrict__ field,
                                                  unsigned short* __restrict__ fT) {
    const int gid = blockIdx.x * 256 + threadIdx.x;
    const int b = gid >> 12;
    const int n = gid & (NNODE - 1);
    const float* hb = hist + ((size_t)b * LHIST * NNODE + n) * CCH;
    float x[LHIST * CCH];
#pragma unroll
    for (int l = 0; l < LHIST; l++) {
        x[l * 3 + 0] = hb[(size_t)l * NNODE * CCH + 0];
        x[l * 3 + 1] = hb[(size_t)l * NNODE * CCH + 1];
        x[l * 3 + 2] = hb[(size_t)l * NNODE * CCH + 2];
    }
    float f[FD];
#pragma unroll
    for (int o = 0; o < FD; o++) f[o] = enc_b2[o] + t2f_b[o];
    for (int j = 0; j < HD; j++) {
        float h = enc_b1[j];
#pragma unroll
        for (int k = 0; k < LHIST * CCH; k++) h += x[k] * enc_w1[k * HD + j];
        h = fmaxf(h, 0.f);
#pragma unroll
        for (int o = 0; o < FD; o++) f[o] += h * enc_w2[j * FD + o];
    }
    const int ti = min(max((int)(x[11 * 3 + 1] * 288.0f), 0), TIDN - 1);
    const int di = min(max((int)(x[11 * 3 + 2] * 7.0f), 0), DIWN - 1);
    for (int g = 0; g < TDD; g++) {
        const float tg = tid_emb[ti * TDD + g];
        const float dg = diw_emb[di * TDD + g];
#pragma unroll
        for (int o = 0; o < FD; o++)
            f[o] += tg * t2f_w[g * FD + o] + dg * t2f_w[(TDD + g) * FD + o];
    }
#pragma unroll
    for (int o4 = 0; o4 < FD / 4; o4++) {
        float4 v = {f[o4 * 4 + 0], f[o4 * 4 + 1], f[o4 * 4 + 2], f[o4 * 4 + 3]};
        *(float4*)&field[(size_t)gid * FD + o4 * 4] = v;
    }
#pragma unroll
    for (int o = 0; o < FD; o++)
        fT[(size_t)(b * FD + o) * NNODE + n] = f2b(f[o]);
}

// ===================== fused GEMM + step (steps 0..2) ================================
// Full-K 128x128 gemm tile -> acc holds Ct for 512 (b,n)-rows x 32 f. Acc -> LDS T,
// then each wave runs the step math on its 128 rows (4 quarters of 32).
// K-loop: distance-2 register prefetch, 2 LDS buffers, unroll-2 ping-pong.
#define TPAD 36
#define QHP  72
#define QFP  40
__global__ __launch_bounds__(256) void gemm_step(const unsigned short* __restrict__ X,
                                                 const unsigned short* __restrict__ Y,
                                                 float* __restrict__ field,
                                                 unsigned short* __restrict__ state,
                                                 unsigned short* __restrict__ fTo,
                                                 const float* __restrict__ pde_w1,
                                                 const float* __restrict__ pde_b1,
                                                 const float* __restrict__ pde_w2,
                                                 const float* __restrict__ pde_b2,
                                                 const float* __restrict__ ss_win,
                                                 const float* __restrict__ ss_wst,
                                                 const float* __restrict__ ss_b,
                                                 const float* __restrict__ ss_wout,
                                                 const float* __restrict__ ss_bout,
                                                 const float* __restrict__ pde_mix,
                                                 int first) {
    constexpr int K = KDIM;
    constexpr int BK = 32;
    __shared__ __align__(16) unsigned short SM0[512 * TPAD];   // dbuf (16384) / T (18432)
    __shared__ __align__(16) unsigned short W1T[HD * FD];
    __shared__ __align__(16) unsigned short W2T[FD * HD];
    __shared__ __align__(16) unsigned short WinT[FD * FD];
    __shared__ __align__(16) unsigned short WstT[FD * FD];
    __shared__ __align__(16) unsigned short WoutT[FD * FD];
    __shared__ __align__(16) unsigned short Hs[4 * 32 * QHP];
    __shared__ __align__(16) unsigned short Fs[4 * 32 * QFP];

    const int tid = threadIdx.x;
    const int wave = tid >> 6;
    const int lane = tid & 63;

    // stage step weights (bf16, transposed)
    for (int i = tid; i < HD * FD; i += 256) W1T[(i & 63) * FD + (i >> 6)] = f2b(pde_w1[i]);
    for (int i = tid; i < HD * FD; i += 256) W2T[(i & 31) * HD + (i >> 5)] = f2b(pde_w2[i]);
    for (int i = tid; i < FD * FD; i += 256) {
        WinT [(i & 31) * FD + (i >> 5)] = f2b(ss_win[i]);
        WstT [(i & 31) * FD + (i >> 5)] = f2b(ss_wst[i]);
        WoutT[(i & 31) * FD + (i >> 5)] = f2b(ss_wout[i]);
    }

    // XCD-aware block remap
    const int l = blockIdx.x + 16 * blockIdx.y;   // 0..511
    const int xcd = l & 7;
    const int rem = l >> 3;
    const int by = xcd * 4 + (rem & 3);           // 0..31
    const int bx = rem >> 2;                      // 0..15
    const int i0 = bx * 128;
    const int j0 = by * 128;
    const int b0 = i0 >> 5;                       // base batch (4 per block)

    const int wi = (wave >> 1) * 64;
    const int wj = (wave & 1) * 64;

    const int lrow = lane >> 2;
    const int gcol = (lane & 3) * 8;
    const int scol = ((lane & 3) ^ ((lane >> 3) & 3)) * 8;

    const unsigned short* Xg = X + (size_t)(i0 + wave * 32 + lrow) * K + gcol;
    const unsigned short* Yg = Y + (size_t)(j0 + wave * 32 + lrow) * K + gcol;
    unsigned short* Xs = SM0;           // [2][4096]
    unsigned short* Ys = SM0 + 8192;    // [2][4096]
    const int ld0 = (wave * 32 + lrow) * BK + scol;
    const int ld1 = (wave * 32 + 16 + lrow) * BK + scol;

    const f32x4 zero = {0.f, 0.f, 0.f, 0.f};
    f32x4 acc[4][4];
#pragma unroll
    for (int a = 0; a < 4; a++)
#pragma unroll
        for (int b = 0; b < 4; b++) acc[a][b] = zero;

    const int fr = lane & 15;
    const int q = lane >> 4;
    const int kq8 = (q ^ ((fr >> 1) & 3)) * 8;

#define GS_COMPUTE(P)                                                              \
    {                                                                              \
        bf16x8 fa[4], fb[4];                                                       \
        _Pragma("unroll") for (int t = 0; t < 4; t++)                              \
            fa[t] = *(const bf16x8*)&Xs[(P) * 4096 + (wi + t * 16 + fr) * BK + kq8]; \
        _Pragma("unroll") for (int t = 0; t < 4; t++)                              \
            fb[t] = *(const bf16x8*)&Ys[(P) * 4096 + (wj + t * 16 + fr) * BK + kq8]; \
        _Pragma("unroll") for (int mi = 0; mi < 4; mi++)                           \
            _Pragma("unroll") for (int ni = 0; ni < 4; ni++)                       \
                acc[mi][ni] = __builtin_amdgcn_mfma_f32_16x16x32_bf16(             \
                    fa[mi], fb[ni], acc[mi][ni], 0, 0, 0);                         \
    }

    // prologue: tiles 0 (A-regs) and 1 (B-regs); A -> buf0
    uint4 ax0 = *(const uint4*)(Xg);
    uint4 ax1 = *(const uint4*)(Xg + 16 * K);
    uint4 ay0 = *(const uint4*)(Yg);
    uint4 ay1 = *(const uint4*)(Yg + 16 * K);
    uint4 bx0 = *(const uint4*)(Xg + BK);
    uint4 bx1 = *(const uint4*)(Xg + BK + 16 * K);
    uint4 by0 = *(const uint4*)(Yg + BK);
    uint4 by1 = *(const uint4*)(Yg + BK + 16 * K);
    *(uint4*)&Xs[ld0] = ax0; *(uint4*)&Xs[ld1] = ax1;
    *(uint4*)&Ys[ld0] = ay0; *(uint4*)&Ys[ld1] = ay1;
    __syncthreads();

    int p = 0;
    for (int kt = 0; kt < K; kt += 2 * BK) {
        if (kt + 2 * BK < K) {
            ax0 = *(const uint4*)(Xg + kt + 2 * BK);
            ax1 = *(const uint4*)(Xg + kt + 2 * BK + 16 * K);
            ay0 = *(const uint4*)(Yg + kt + 2 * BK);
            ay1 = *(const uint4*)(Yg + kt + 2 * BK + 16 * K);
        }
        GS_COMPUTE(p);
        {
            const int np = p ^ 1;
            *(uint4*)&Xs[np * 4096 + ld0] = bx0; *(uint4*)&Xs[np * 4096 + ld1] = bx1;
            *(uint4*)&Ys[np * 4096 + ld0] = by0; *(uint4*)&Ys[np * 4096 + ld1] = by1;
            __syncthreads();
        }
        if (kt + 3 * BK < K) {
            bx0 = *(const uint4*)(Xg + kt + 3 * BK);
            bx1 = *(const uint4*)(Xg + kt + 3 * BK + 16 * K);
            by0 = *(const uint4*)(Yg + kt + 3 * BK);
            by1 = *(const uint4*)(Yg + kt + 3 * BK + 16 * K);
        }
        GS_COMPUTE(p ^ 1);
        if (kt + 2 * BK < K) {
            *(uint4*)&Xs[p * 4096 + ld0] = ax0; *(uint4*)&Xs[p * 4096 + ld1] = ax1;
            *(uint4*)&Ys[p * 4096 + ld0] = ay0; *(uint4*)&Ys[p * 4096 + ld1] = ay1;
            __syncthreads();
        }
    }
#undef GS_COMPUTE

    // ---- acc -> T (Ct, bf16): T[(bb*128 + nl)*TPAD + f] ----
    __syncthreads();   // all LDS frag reads of last tile done before overwrite
    unsigned short* T = SM0;
    const int r0 = q * 4;
#pragma unroll
    for (int mi = 0; mi < 4; mi++) {
#pragma unroll
        for (int ni = 0; ni < 4; ni++) {
            const int R0 = i0 + wi + mi * 16 + r0;
            const int nl = wj + ni * 16 + fr;
            ushort4 pk = {f2b(acc[mi][ni][0]), f2b(acc[mi][ni][1]),
                          f2b(acc[mi][ni][2]), f2b(acc[mi][ni][3])};
            *(ushort4*)&T[((((R0 >> 5) & 3) << 7) + nl) * TPAD + (R0 & 31)] = pk;
        }
    }
    __syncthreads();

    // ---- step math: wave handles rows [wave*128, +128) in 4 quarters of 32 ----
    const int ln = fr;
    const int kq = q * 8;
    unsigned short* Hw = &Hs[wave * 32 * QHP];
    unsigned short* Fw = &Fs[wave * 32 * QFP];
    const float alpha = 1.f / (1.f + __expf(-pde_mix[0]));
    const float dt = 0.25f;

    bf16x8 w1f[4], w2f[2][2], winf[2], wstf[2], woutf[2];
#pragma unroll
    for (int nj = 0; nj < 4; nj++) w1f[nj] = ldsfrag(&W1T[(nj * 16 + ln) * FD + kq]);
#pragma unroll
    for (int nf = 0; nf < 2; nf++) {
#pragma unroll
        for (int kk = 0; kk < 2; kk++)
            w2f[nf][kk] = ldsfrag(&W2T[(nf * 16 + ln) * HD + kk * 32 + kq]);
        winf[nf]  = ldsfrag(&WinT [(nf * 16 + ln) * FD + kq]);
        wstf[nf]  = ldsfrag(&WstT [(nf * 16 + ln) * FD + kq]);
        woutf[nf] = ldsfrag(&WoutT[(nf * 16 + ln) * FD + kq]);
    }
    float b1v[4], b2v[2], bsv[2], bov[2];
#pragma unroll
    for (int nj = 0; nj < 4; nj++) b1v[nj] = pde_b1[nj * 16 + ln];
#pragma unroll
    for (int nf = 0; nf < 2; nf++) {
        b2v[nf] = pde_b2[nf * 16 + ln];
        bsv[nf] = ss_b[nf * 16 + ln];
        bov[nf] = ss_bout[nf * 16 + ln];
    }

    for (int qtr = 0; qtr < 4; qtr++) {
        const int lb = wave * 128 + qtr * 32;     // local row base in T
        const int bb = lb >> 7;
        const int nl0 = lb & 127;
        const int bg = b0 + bb;
        const int mwg = (bg << 12) + j0 + nl0;    // global (b,n) row base (32 rows)

        bf16x8 fA[2], stA[2];
#pragma unroll
        for (int mi = 0; mi < 2; mi++) {
            const float4* fp = (const float4*)&field[(size_t)(mwg + mi * 16 + ln) * FD + kq];
            fA[mi] = pack8(fp[0], fp[1]);
        }
        if (!first) {
#pragma unroll
            for (int mi = 0; mi < 2; mi++)
                stA[mi] = *(const bf16x8*)&state[(size_t)(mwg + mi * 16 + ln) * FD + kq];
        }

        // H = relu(field @ w1 + b1)
        f32x4 hc[2][4];
#pragma unroll
        for (int mi = 0; mi < 2; mi++)
#pragma unroll
            for (int nj = 0; nj < 4; nj++)
                hc[mi][nj] = __builtin_amdgcn_mfma_f32_16x16x32_bf16(fA[mi], w1f[nj], zero, 0, 0, 0);
#pragma unroll
        for (int mi = 0; mi < 2; mi++)
#pragma unroll
            for (int nj = 0; nj < 4; nj++)
#pragma unroll
                for (int r = 0; r < 4; r++)
                    Hw[(mi * 16 + r0 + r) * QHP + nj * 16 + ln] =
                        f2b(fmaxf(hc[mi][nj][r] + b1v[nj], 0.f));

        // field + Ct in C-layout
        float fld[2][2][4], ctv[2][2][4];
#pragma unroll
        for (int mi = 0; mi < 2; mi++)
#pragma unroll
            for (int nf = 0; nf < 2; nf++)
#pragma unroll
                for (int r = 0; r < 4; r++) {
                    const size_t idx = (size_t)(mwg + mi * 16 + r0 + r) * FD + nf * 16 + ln;
                    fld[mi][nf][r] = field[idx];
                    ctv[mi][nf][r] = b2f(T[(lb + mi * 16 + r0 + r) * TPAD + nf * 16 + ln]);
                }

        // N_F = H @ w2 + b2
        bf16x8 hA[2][2];
#pragma unroll
        for (int mi = 0; mi < 2; mi++)
#pragma unroll
            for (int kk = 0; kk < 2; kk++)
                hA[mi][kk] = ldsfrag(&Hw[(mi * 16 + ln) * QHP + kk * 32 + kq]);
        f32x4 nc[2][2];
#pragma unroll
        for (int mi = 0; mi < 2; mi++)
#pragma unroll
            for (int nf = 0; nf < 2; nf++) {
                f32x4 a = __builtin_amdgcn_mfma_f32_16x16x32_bf16(hA[mi][0], w2f[nf][0], zero, 0, 0, 0);
                nc[mi][nf] = __builtin_amdgcn_mfma_f32_16x16x32_bf16(hA[mi][1], w2f[nf][1], a, 0, 0, 0);
            }

        // fe
        float fe[2][2][4];
#pragma unroll
        for (int mi = 0; mi < 2; mi++)
#pragma unroll
            for (int nf = 0; nf < 2; nf++)
#pragma unroll
                for (int r = 0; r < 4; r++) {
                    const float nfv = nc[mi][nf][r] + b2v[nf];
                    const float fv = fld[mi][nf][r];
                    fe[mi][nf][r] = fv + (alpha * (ctv[mi][nf][r] - fv) + (1.f - alpha) * nfv) * dt;
                    Fw[(mi * 16 + r0 + r) * QFP + nf * 16 + ln] = f2b(fe[mi][nf][r]);
                }

        // S = tanh(fe @ win + st @ wst + b)
        bf16x8 feA[2];
#pragma unroll
        for (int mi = 0; mi < 2; mi++) feA[mi] = ldsfrag(&Fw[(mi * 16 + ln) * QFP + kq]);
        f32x4 sc_[2][2];
#pragma unroll
        for (int mi = 0; mi < 2; mi++)
#pragma unroll
            for (int nf = 0; nf < 2; nf++) {
                f32x4 a = __builtin_amdgcn_mfma_f32_16x16x32_bf16(feA[mi], winf[nf], zero, 0, 0, 0);
                if (!first)
                    a = __builtin_amdgcn_mfma_f32_16x16x32_bf16(stA[mi], wstf[nf], a, 0, 0, 0);
                sc_[mi][nf] = a;
            }
        float sval[2][2][4];
#pragma unroll
        for (int mi = 0; mi < 2; mi++)
#pragma unroll
            for (int nf = 0; nf < 2; nf++)
#pragma unroll
                for (int r = 0; r < 4; r++)
                    sval[mi][nf][r] = fast_tanh(sc_[mi][nf][r] + bsv[nf]);
#pragma unroll
        for (int mi = 0; mi < 2; mi++)
#pragma unroll
            for (int nf = 0; nf < 2; nf++)
#pragma unroll
                for (int r = 0; r < 4; r++)
                    Fw[(mi * 16 + r0 + r) * QFP + nf * 16 + ln] = f2b(sval[mi][nf][r]);

        // field_new = fe + S @ wout + bout; stores
        bf16x8 SA[2];
#pragma unroll
        for (int mi = 0; mi < 2; mi++) SA[mi] = ldsfrag(&Fw[(mi * 16 + ln) * QFP + kq]);
#pragma unroll
        for (int mi = 0; mi < 2; mi++) {
#pragma unroll
            for (int nf = 0; nf < 2; nf++) {
                f32x4 oc = __builtin_amdgcn_mfma_f32_16x16x32_bf16(SA[mi], woutf[nf], zero, 0, 0, 0);
                float fnew[4];
#pragma unroll
                for (int r = 0; r < 4; r++) {
                    fnew[r] = fe[mi][nf][r] + oc[r] + bov[nf];
                    const size_t idx = (size_t)(mwg + mi * 16 + r0 + r) * FD + nf * 16 + ln;
                    field[idx] = fnew[r];
                    state[idx] = f2b(sval[mi][nf][r]);
                }
                ushort4 pk = {f2b(fnew[0]), f2b(fnew[1]), f2b(fnew[2]), f2b(fnew[3])};
                const size_t fta = (size_t)(bg * FD + nf * 16 + ln) * NNODE
                                 + j0 + nl0 + mi * 16 + r0;
                *(ushort4*)&fTo[fta] = pk;
            }
        }
    }
}

// ---------------- split-K GEMM (last step), distance-2 prefetch ----------------------
__global__ __launch_bounds__(256) void gemm_bt(const unsigned short* __restrict__ X,
                                               const unsigned short* __restrict__ Y,
                                               unsigned short* __restrict__ Cp) {
    constexpr int K = KDIM;
    constexpr int KS = KDIM / 2;
    constexpr int BK = 32;
    __shared__ __align__(16) unsigned short Xs[2 * 4096];
    __shared__ __align__(16) unsigned short Ys[2 * 4096];
    const int tid = threadIdx.x;
    const int wave = tid >> 6;
    const int lane = tid & 63;

    const int l = blockIdx.x + 16 * blockIdx.y;
    const int xcd = l & 7;
    const int rem = l >> 3;
    const int by = xcd * 4 + (rem & 3);
    const int bx = rem >> 2;
    const int i0 = bx * 128;
    const int j0 = by * 128;
    const int k0 = blockIdx.z * KS;
    unsigned short* C = Cp + (size_t)blockIdx.z * MTOT * FD;

    const int wi = (wave >> 1) * 64;
    const int wj = (wave & 1) * 64;

    const int lrow = lane >> 2;
    const int gcol = (lane & 3) * 8;
    const int scol = ((lane & 3) ^ ((lane >> 3) & 3)) * 8;

    const unsigned short* Xg = X + (size_t)(i0 + wave * 32 + lrow) * K + k0 + gcol;
    const unsigned short* Yg = Y + (size_t)(j0 + wave * 32 + lrow) * K + k0 + gcol;
    const int ld0 = (wave * 32 + lrow) * BK + scol;
    const int ld1 = (wave * 32 + 16 + lrow) * BK + scol;

    const f32x4 zero = {0.f, 0.f, 0.f, 0.f};
    f32x4 acc[4][4];
#pragma unroll
    for (int a = 0; a < 4; a++)
#pragma unroll
        for (int b = 0; b < 4; b++) acc[a][b] = zero;

    const int fr = lane & 15;
    const int q = lane >> 4;
    const int kq8 = (q ^ ((fr >> 1) & 3)) * 8;

#define GB_COMPUTE(P)                                                              \
    {                                                                              \
        bf16x8 fa[4], fb[4];                                                       \
        _Pragma("unroll") for (int t = 0; t < 4; t++)                              \
            fa[t] = *(const bf16x8*)&Xs[(P) * 4096 + (wi + t * 16 + fr) * BK + kq8]; \
        _Pragma("unroll") for (int t = 0; t < 4; t++)                              \
            fb[t] = *(const bf16x8*)&Ys[(P) * 4096 + (wj + t * 16 + fr) * BK + kq8]; \
        _Pragma("unroll") for (int mi = 0; mi < 4; mi++)                           \
            _Pragma("unroll") for (int ni = 0; ni < 4; ni++)                       \
                acc[mi][ni] = __builtin_amdgcn_mfma_f32_16x16x32_bf16(             \
                    fa[mi], fb[ni], acc[mi][ni], 0, 0, 0);                         \
    }

    uint4 ax0 = *(const uint4*)(Xg);
    uint4 ax1 = *(const uint4*)(Xg + 16 * K);
    uint4 ay0 = *(const uint4*)(Yg);
    uint4 ay1 = *(const uint4*)(Yg + 16 * K);
    uint4 bx0 = *(const uint4*)(Xg + BK);
    uint4 bx1 = *(const uint4*)(Xg + BK + 16 * K);
    uint4 by0 = *(const uint4*)(Yg + BK);
    uint4 by1 = *(const uint4*)(Yg + BK + 16 * K);
    *(uint4*)&Xs[ld0] = ax0; *(uint4*)&Xs[ld1] = ax1;
    *(uint4*)&Ys[ld0] = ay0; *(uint4*)&Ys[ld1] = ay1;
    __syncthreads();

    int p = 0;
    for (int kt = 0; kt < KS; kt += 2 * BK) {
        if (kt + 2 * BK < KS) {
            ax0 = *(const uint4*)(Xg + kt + 2 * BK);
            ax1 = *(const uint4*)(Xg + kt + 2 * BK + 16 * K);
            ay0 = *(const uint4*)(Yg + kt + 2 * BK);
            ay1 = *(const uint4*)(Yg + kt + 2 * BK + 16 * K);
        }
        GB_COMPUTE(p);
        {
            const int np = p ^ 1;
            *(uint4*)&Xs[np * 4096 + ld0] = bx0; *(uint4*)&Xs[np * 4096 + ld1] = bx1;
            *(uint4*)&Ys[np * 4096 + ld0] = by0; *(uint4*)&Ys[np * 4096 + ld1] = by1;
            __syncthreads();
        }
        if (kt + 3 * BK < KS) {
            bx0 = *(const uint4*)(Xg + kt + 3 * BK);
            bx1 = *(const uint4*)(Xg + kt + 3 * BK + 16 * K);
            by0 = *(const uint4*)(Yg + kt + 3 * BK);
            by1 = *(const uint4*)(Yg + kt + 3 * BK + 16 * K);
        }
        GB_COMPUTE(p ^ 1);
        if (kt + 2 * BK < KS) {
            *(uint4*)&Xs[p * 4096 + ld0] = ax0; *(uint4*)&Xs[p * 4096 + ld1] = ax1;
            *(uint4*)&Ys[p * 4096 + ld0] = ay0; *(uint4*)&Ys[p * 4096 + ld1] = ay1;
            __syncthreads();
        }
    }
#undef GB_COMPUTE

    const int r0 = q * 4;
#pragma unroll
    for (int mi = 0; mi < 4; mi++) {
#pragma unroll
        for (int ni = 0; ni < 4; ni++) {
            const int R0 = i0 + wi + mi * 16 + r0;
            const int col = j0 + wj + ni * 16 + fr;
            const size_t addr = ((size_t)(R0 >> 5) * NNODE + col) * FD + (R0 & 31);
            ushort4 pk = {f2b(acc[mi][ni][0]), f2b(acc[mi][ni][1]),
                          f2b(acc[mi][ni][2]), f2b(acc[mi][ni][3])};
            *(ushort4*)&C[addr] = pk;
        }
    }
}

// ---------------- last step: MFMA step + fused decoder (R5, last=1 path) -------------
#define HPAD 72
#define FPAD 40
__global__ __launch_bounds__(256, 2) void step_mfma(const unsigned short* __restrict__ Ct0,
                                                    const unsigned short* __restrict__ Ct1,
                                                    float* __restrict__ field,
                                                    unsigned short* __restrict__ state,
                                                    const float* __restrict__ pde_w1,
                                                    const float* __restrict__ pde_b1,
                                                    const float* __restrict__ pde_w2,
                                                    const float* __restrict__ pde_b2,
                                                    const float* __restrict__ ss_win,
                                                    const float* __restrict__ ss_wst,
                                                    const float* __restrict__ ss_b,
                                                    const float* __restrict__ ss_wout,
                                                    const float* __restrict__ ss_bout,
                                                    const float* __restrict__ pde_mix,
                                                    const float* __restrict__ dec_w1,
                                                    const float* __restrict__ dec_b1,
                                                    const float* __restrict__ dec_w2,
                                                    const float* __restrict__ dec_b2,
                                                    float* __restrict__ out) {
    __shared__ __align__(16) unsigned short W1T[HD * FD];
    __shared__ __align__(16) unsigned short W2T[FD * HD];
    __shared__ __align__(16) unsigned short WinT[FD * FD];
    __shared__ __align__(16) unsigned short WstT[FD * FD];
    __shared__ __align__(16) unsigned short WoutT[FD * FD];
    __shared__ __align__(16) unsigned short Wd1T[HD * FD];
    __shared__ __align__(16) unsigned short Wd2T[16 * HD];
    __shared__ __align__(16) unsigned short Hs[4 * 64 * HPAD];
    __shared__ __align__(16) unsigned short Fs[4 * 64 * FPAD];

    const int tid = threadIdx.x;
    for (int i = tid; i < HD * FD; i += 256) W1T[(i & 63) * FD + (i >> 6)] = f2b(pde_w1[i]);
    for (int i = tid; i < HD * FD; i += 256) W2T[(i & 31) * HD + (i >> 5)] = f2b(pde_w2[i]);
    for (int i = tid; i < FD * FD; i += 256) {
        WinT [(i & 31) * FD + (i >> 5)] = f2b(ss_win[i]);
        WstT [(i & 31) * FD + (i >> 5)] = f2b(ss_wst[i]);
        WoutT[(i & 31) * FD + (i >> 5)] = f2b(ss_wout[i]);
    }
    for (int i = tid; i < HD * FD; i += 256)
        Wd1T[(i & 63) * FD + (i >> 6)] = f2b(dec_w1[i]);
    for (int i = tid; i < 16 * HD; i += 256) {
        const int o = i >> 6, j = i & 63;
        Wd2T[i] = (o < OUTD) ? f2b(dec_w2[j * OUTD + o]) : (unsigned short)0;
    }
    __syncthreads();

    const int wv = tid >> 6;
    const int lane = tid & 63;
    const int ln = lane & 15;
    const int q = lane >> 4;
    const int kq = q * 8;
    const int r0 = q * 4;
    const int mw = blockIdx.x * 256 + wv * 64;
    const int b = mw >> 12;
    const int n0 = mw & (NNODE - 1);
    unsigned short* Hw = &Hs[wv * 64 * HPAD];
    unsigned short* Fw = &Fs[wv * 64 * FPAD];

    const float alpha = 1.f / (1.f + __expf(-pde_mix[0]));
    const float dt = 0.25f;

    bf16x8 w1f[4], w2f[2][2], winf[2], wstf[2], woutf[2];
#pragma unroll
    for (int nj = 0; nj < 4; nj++) w1f[nj] = ldsfrag(&W1T[(nj * 16 + ln) * FD + kq]);
#pragma unroll
    for (int nf = 0; nf < 2; nf++) {
#pragma unroll
        for (int kk = 0; kk < 2; kk++)
            w2f[nf][kk] = ldsfrag(&W2T[(nf * 16 + ln) * HD + kk * 32 + kq]);
        winf[nf]  = ldsfrag(&WinT [(nf * 16 + ln) * FD + kq]);
        wstf[nf]  = ldsfrag(&WstT [(nf * 16 + ln) * FD + kq]);
        woutf[nf] = ldsfrag(&WoutT[(nf * 16 + ln) * FD + kq]);
    }

    float b1v[4], b2v[2], bsv[2], bov[2];
#pragma unroll
    for (int nj = 0; nj < 4; nj++) b1v[nj] = pde_b1[nj * 16 + ln];
#pragma unroll
    for (int nf = 0; nf < 2; nf++) {
        b2v[nf] = pde_b2[nf * 16 + ln];
        bsv[nf] = ss_b[nf * 16 + ln];
        bov[nf] = ss_bout[nf * 16 + ln];
    }

    bf16x8 fA[4], stA[4];
#pragma unroll
    for (int mi = 0; mi < 4; mi++) {
        const float4* fp = (const float4*)&field[(size_t)(mw + mi * 16 + ln) * FD + kq];
        fA[mi] = pack8(fp[0], fp[1]);
    }
#pragma unroll
    for (int mi = 0; mi < 4; mi++)
        stA[mi] = *(const bf16x8*)&state[(size_t)(mw + mi * 16 + ln) * FD + kq];

    const f32x4 zero = {0.f, 0.f, 0.f, 0.f};

    f32x4 hc[4][4];
#pragma unroll
    for (int mi = 0; mi < 4; mi++)
#pragma unroll
        for (int nj = 0; nj < 4; nj++)
            hc[mi][nj] = __builtin_amdgcn_mfma_f32_16x16x32_bf16(fA[mi], w1f[nj], zero, 0, 0, 0);
#pragma unroll
    for (int mi = 0; mi < 4; mi++)
#pragma unroll
        for (int nj = 0; nj < 4; nj++)
#pragma unroll
            for (int r = 0; r < 4; r++)
                Hw[(mi * 16 + r0 + r) * HPAD + nj * 16 + ln] =
                    f2b(fmaxf(hc[mi][nj][r] + b1v[nj], 0.f));

    float fld[4][2][4], ctv[4][2][4];
#pragma unroll
    for (int mi = 0; mi < 4; mi++)
#pragma unroll
        for (int nf = 0; nf < 2; nf++)
#pragma unroll
            for (int r = 0; r < 4; r++) {
                const size_t idx = (size_t)(mw + mi * 16 + r0 + r) * FD + nf * 16 + ln;
                fld[mi][nf][r] = field[idx];
                ctv[mi][nf][r] = b2f(Ct0[idx]) + b2f(Ct1[idx]);
            }

    bf16x8 hA[4][2];
#pragma unroll
    for (int mi = 0; mi < 4; mi++)
#pragma unroll
        for (int kk = 0; kk < 2; kk++)
            hA[mi][kk] = ldsfrag(&Hw[(mi * 16 + ln) * HPAD + kk * 32 + kq]);
    f32x4 nc[4][2];
#pragma unroll
    for (int mi = 0; mi < 4; mi++)
#pragma unroll
        for (int nf = 0; nf < 2; nf++) {
            f32x4 a = __builtin_amdgcn_mfma_f32_16x16x32_bf16(hA[mi][0], w2f[nf][0], zero, 0, 0, 0);
            nc[mi][nf] = __builtin_amdgcn_mfma_f32_16x16x32_bf16(hA[mi][1], w2f[nf][1], a, 0, 0, 0);
        }

    float fe[4][2][4];
#pragma unroll
    for (int mi = 0; mi < 4; mi++)
#pragma unroll
        for (int nf = 0; nf < 2; nf++)
#pragma unroll
            for (int r = 0; r < 4; r++) {
                const float nfv = nc[mi][nf][r] + b2v[nf];
                const float fv = fld[mi][nf][r];
                fe[mi][nf][r] = fv + (alpha * (ctv[mi][nf][r] - fv) + (1.f - alpha) * nfv) * dt;
                Fw[(mi * 16 + r0 + r) * FPAD + nf * 16 + ln] = f2b(fe[mi][nf][r]);
            }

    bf16x8 feA[4];
#pragma unroll
    for (int mi = 0; mi < 4; mi++) feA[mi] = ldsfrag(&Fw[(mi * 16 + ln) * FPAD + kq]);
    f32x4 sc_[4][2];
#pragma unroll
    for (int mi = 0; mi < 4; mi++)
#pragma unroll
        for (int nf = 0; nf < 2; nf++) {
            f32x4 a = __builtin_amdgcn_mfma_f32_16x16x32_bf16(feA[mi], winf[nf], zero, 0, 0, 0);
            a = __builtin_amdgcn_mfma_f32_16x16x32_bf16(stA[mi], wstf[nf], a, 0, 0, 0);
            sc_[mi][nf] = a;
        }
    float sval[4][2][4];
#pragma unroll
    for (int mi = 0; mi < 4; mi++)
#pragma unroll
        for (int nf = 0; nf < 2; nf++)
#pragma unroll
            for (int r = 0; r < 4; r++)
                sval[mi][nf][r] = fast_tanh(sc_[mi][nf][r] + bsv[nf]);
#pragma unroll
    for (int mi = 0; mi < 4; mi++)
#pragma unroll
        for (int nf = 0; nf < 2; nf++)
#pragma unroll
            for (int r = 0; r < 4; r++)
                Fw[(mi * 16 + r0 + r) * FPAD + nf * 16 + ln] = f2b(sval[mi][nf][r]);

    bf16x8 SA[4];
#pragma unroll
    for (int mi = 0; mi < 4; mi++) SA[mi] = ldsfrag(&Fw[(mi * 16 + ln) * FPAD + kq]);
    float fnew[4][2][4];
#pragma unroll
    for (int mi = 0; mi < 4; mi++)
#pragma unroll
        for (int nf = 0; nf < 2; nf++) {
            f32x4 oc = __builtin_amdgcn_mfma_f32_16x16x32_bf16(SA[mi], woutf[nf], zero, 0, 0, 0);
#pragma unroll
            for (int r = 0; r < 4; r++)
                fnew[mi][nf][r] = fe[mi][nf][r] + oc[r] + bov[nf];
        }

    // fused decoder
    bf16x8 wd1f[4], wd2f[2];
#pragma unroll
    for (int nj = 0; nj < 4; nj++) wd1f[nj] = ldsfrag(&Wd1T[(nj * 16 + ln) * FD + kq]);
#pragma unroll
    for (int kk = 0; kk < 2; kk++) wd2f[kk] = ldsfrag(&Wd2T[ln * HD + kk * 32 + kq]);
    float db1v[4];
#pragma unroll
    for (int nj = 0; nj < 4; nj++) db1v[nj] = dec_b1[nj * 16 + ln];
    const float db2v = (ln < OUTD) ? dec_b2[ln] : 0.f;

#pragma unroll
    for (int mi = 0; mi < 4; mi++)
#pragma unroll
        for (int nf = 0; nf < 2; nf++)
#pragma unroll
            for (int r = 0; r < 4; r++)
                Fw[(mi * 16 + r0 + r) * FPAD + nf * 16 + ln] = f2b(fnew[mi][nf][r]);
    bf16x8 fnA[4];
#pragma unroll
    for (int mi = 0; mi < 4; mi++) fnA[mi] = ldsfrag(&Fw[(mi * 16 + ln) * FPAD + kq]);

    f32x4 h2[4][4];
#pragma unroll
    for (int mi = 0; mi < 4; mi++)
#pragma unroll
        for (int nj = 0; nj < 4; nj++)
            h2[mi][nj] = __builtin_amdgcn_mfma_f32_16x16x32_bf16(fnA[mi], wd1f[nj], zero, 0, 0, 0);
#pragma unroll
    for (int mi = 0; mi < 4; mi++)
#pragma unroll
        for (int nj = 0; nj < 4; nj++)
#pragma unroll
            for (int r = 0; r < 4; r++)
                Hw[(mi * 16 + r0 + r) * HPAD + nj * 16 + ln] =
                    f2b(fmaxf(h2[mi][nj][r] + db1v[nj], 0.f));
    bf16x8 h2A[4][2];
#pragma unroll
    for (int mi = 0; mi < 4; mi++)
#pragma unroll
        for (int kk = 0; kk < 2; kk++)
            h2A[mi][kk] = ldsfrag(&Hw[(mi * 16 + ln) * HPAD + kk * 32 + kq]);
#pragma unroll
    for (int mi = 0; mi < 4; mi++) {
        f32x4 a = __builtin_amdgcn_mfma_f32_16x16x32_bf16(h2A[mi][0], wd2f[0], zero, 0, 0, 0);
        a = __builtin_amdgcn_mfma_f32_16x16x32_bf16(h2A[mi][1], wd2f[1], a, 0, 0, 0);
        if (ln < OUTD) {
            float4 v = {a[0] + db2v, a[1] + db2v, a[2] + db2v, a[3] + db2v};
            *(float4*)&out[(size_t)(b * OUTD + ln) * NNODE + n0 + mi * 16 + r0] = v;
        }
    }
}

extern "C" void kernel_launch(void* const* d_in, const int* in_sizes, int n_in,
                              void* d_out, int out_size, void* d_ws, size_t ws_size,
                              hipStream_t stream) {
    (void)in_sizes; (void)n_in; (void)out_size; (void)ws_size;
    const float* hist    = (const float*)d_in[0];
    const float* tid_emb = (const float*)d_in[5];
    const float* diw_emb = (const float*)d_in[6];
    const float* t2f_w   = (const float*)d_in[7];
    const float* t2f_b   = (const float*)d_in[8];
    const float* enc_w1  = (const float*)d_in[9];
    const float* enc_b1  = (const float*)d_in[10];
    const float* enc_w2  = (const float*)d_in[11];
    const float* enc_b2  = (const float*)d_in[12];
    const float* node_emb= (const float*)d_in[13];
    const float* pde_w1  = (const float*)d_in[14];
    const float* pde_b1  = (const float*)d_in[15];
    const float* pde_w2  = (const float*)d_in[16];
    const float* pde_b2  = (const float*)d_in[17];
    const float* ss_win  = (const float*)d_in[18];
    const float* ss_wst  = (const float*)d_in[19];
    const float* ss_b    = (const float*)d_in[20];
    const float* ss_wout = (const float*)d_in[21];
    const float* ss_bout = (const float*)d_in[22];
    const float* dec_w1  = (const float*)d_in[23];
    const float* dec_b1  = (const float*)d_in[24];
    const float* dec_w2  = (const float*)d_in[25];
    const float* dec_b2  = (const float*)d_in[26];
    const float* pde_mix = (const float*)d_in[27];

    char* w = (char*)d_ws;
    unsigned short* A_bf = (unsigned short*)w;  w += (size_t)KDIM * KDIM * 2;   // 33.5 MB
    unsigned short* fTa  = (unsigned short*)w;  w += (size_t)MROWS * KDIM * 2;  // 16.8 MB
    unsigned short* fTb  = (unsigned short*)w;  w += (size_t)MROWS * KDIM * 2;  // 16.8 MB
    float* field = (float*)w;                   w += (size_t)MTOT * FD * 4;     // 33.5 MB
    unsigned short* state = (unsigned short*)w; w += (size_t)MTOT * FD * 2;     // 16.8 MB
    unsigned short* Cp    = (unsigned short*)w; w += (size_t)2 * MTOT * FD * 2; // 33.5 MB

    build_A<<<NNODE, 256, 0, stream>>>(node_emb, A_bf);
    encoder<<<(BATCH * NNODE) / 256, 256, 0, stream>>>(hist, tid_emb, diw_emb, t2f_w,
                                                       t2f_b, enc_w1, enc_b1, enc_w2,
                                                       enc_b2, field, fTa);
    // steps 0..2: fused gemm+step, fT ping-pong a->b->a->b
    unsigned short* fts[4] = {fTa, fTb, fTa, fTb};
    for (int s = 0; s < 3; s++) {
        gemm_step<<<dim3(16, 32), 256, 0, stream>>>(
            fts[s], A_bf, field, state, fts[s + 1], pde_w1, pde_b1, pde_w2, pde_b2,
            ss_win, ss_wst, ss_b, ss_wout, ss_bout, pde_mix, s == 0 ? 1 : 0);
    }
    // step 3: split-K gemm + step with fused decoder
    gemm_bt<<<dim3(16, 32, 2), 256, 0, stream>>>(fts[3], A_bf, Cp);
    step_mfma<<<MTOT / 256, 256, 0, stream>>>(
        Cp, Cp + (size_t)MTOT * FD, field, state, pde_w1, pde_b1, pde_w2, pde_b2,
        ss_win, ss_wst, ss_b, ss_wout, ss_bout, pde_mix,
        dec_w1, dec_b1, dec_w2, dec_b2, (float*)d_out);
}